// Round 4
// baseline (182.302 us; speedup 1.0000x reference)
//
#include <hip/hip_runtime.h>

typedef __bf16 bf16x8 __attribute__((ext_vector_type(8)));
typedef float f32x4 __attribute__((ext_vector_type(4)));
typedef unsigned short us4 __attribute__((ext_vector_type(4)));
typedef unsigned short us8v __attribute__((ext_vector_type(8)));

__device__ __forceinline__ unsigned short f2bf(float f) {
  unsigned int u = __builtin_bit_cast(unsigned int, f);
  u += 0x7fffu + ((u >> 16) & 1u);
  return (unsigned short)(u >> 16);
}
__device__ __forceinline__ float bf2f(unsigned short s) {
  unsigned int u = ((unsigned int)s) << 16;
  return __builtin_bit_cast(float, u);
}
__device__ __forceinline__ f32x4 mfma16(bf16x8 a, bf16x8 b, f32x4 c) {
  return __builtin_amdgcn_mfma_f32_16x16x32_bf16(a, b, c, 0, 0, 0);
}
__device__ __forceinline__ void gload16(const void* g, void* l) {
  __builtin_amdgcn_global_load_lds(
      (const __attribute__((address_space(1))) unsigned int*)g,
      (__attribute__((address_space(3))) unsigned int*)l, 16, 0, 0);
}
template <int CTRL>
__device__ __forceinline__ float dppf(float x) {
  return __builtin_bit_cast(
      float, __builtin_amdgcn_mov_dpp(__builtin_bit_cast(int, x), CTRL, 0xf, 0xf, true));
}
__device__ __forceinline__ float rmax16(float x) {
  x = fmaxf(x, dppf<0xB1>(x));
  x = fmaxf(x, dppf<0x4E>(x));
  x = fmaxf(x, dppf<0x124>(x));
  x = fmaxf(x, dppf<0x128>(x));
  return x;
}
__device__ __forceinline__ float rsum16(float x) {
  x += dppf<0xB1>(x);
  x += dppf<0x4E>(x);
  x += dppf<0x124>(x);
  x += dppf<0x128>(x);
  return x;
}

// ---------------- transpose+cast 4 weights [1024][1024] f32 -> [N][K] bf16 ----------------
__global__ __launch_bounds__(256) void transpose_cast4(
    const float* __restrict__ w0, const float* __restrict__ w1,
    const float* __restrict__ w2, const float* __restrict__ w3,
    unsigned short* __restrict__ o0, unsigned short* __restrict__ o1,
    unsigned short* __restrict__ o2, unsigned short* __restrict__ o3) {
  __shared__ float t[32][33];
  const int z = blockIdx.z;
  const float* in = z == 0 ? w0 : (z == 1 ? w1 : (z == 2 ? w2 : w3));
  unsigned short* out = z == 0 ? o0 : (z == 1 ? o1 : (z == 2 ? o2 : o3));
  int k0 = blockIdx.y * 32;
  int n0 = blockIdx.x * 32;
  int r = threadIdx.x >> 5;
  int c = threadIdx.x & 31;
#pragma unroll
  for (int s = 0; s < 4; ++s)
    t[r + s * 8][c] = in[(k0 + r + s * 8) * 1024 + n0 + c];
  __syncthreads();
#pragma unroll
  for (int s = 0; s < 4; ++s)
    out[(n0 + r + s * 8) * 1024 + k0 + c] = f2bf(t[c][r + s * 8]);
}

// ---------------- segmask: pack {bf16(-1e30*mask), bf16(seg)} per (b,i,j) ----------------
__global__ __launch_bounds__(256) void segmask_kernel(const unsigned char* __restrict__ seg,
                                                      const float* __restrict__ mask,
                                                      unsigned int* __restrict__ out) {
  int ij = blockIdx.x * 256 + threadIdx.x;
  unsigned short sv = *(const unsigned short*)&seg[ij * 2];
  float2 mv = *(const float2*)&mask[(size_t)ij * 2];
  unsigned int o0 = ((unsigned int)f2bf(mv.x * -1e30f) << 16) | ((sv & 0xffu) ? 0x3f80u : 0u);
  unsigned int o1 = ((unsigned int)f2bf(mv.y * -1e30f) << 16) | ((sv >> 8) ? 0x3f80u : 0u);
  out[ij] = o0;
  out[1048576 + ij] = o1;
}

// ---------------- all 4 projections, 2-phase dbuf pipeline, f32 A reg-staged ----------------
__global__ __launch_bounds__(256) void proj4_kernel(
    const float* __restrict__ hf, const float* __restrict__ rf,
    const unsigned short* __restrict__ wq_t, const unsigned short* __restrict__ wk_t,
    const unsigned short* __restrict__ wv_t, const unsigned short* __restrict__ wr_t,
    const float* __restrict__ rwb, const float* __restrict__ rrb, const float* __restrict__ rsb,
    unsigned short* __restrict__ qwb, unsigned short* __restrict__ qrb,
    unsigned short* __restrict__ qsb,
    unsigned short* __restrict__ khb, unsigned short* __restrict__ vhb,
    unsigned short* __restrict__ krhb) {
  __shared__ unsigned short sA[2][128 * 32];
  __shared__ unsigned short sB[2][128 * 32];
  const int bx = blockIdx.x;
  int sel, rblk;
  const float* Af;
  if (bx < 384) { sel = bx >> 7; rblk = bx & 127; Af = hf; }
  else { sel = 3; rblk = bx - 384; Af = rf; }
  const unsigned short* Bt = sel == 0 ? wq_t : (sel == 1 ? wk_t : (sel == 2 ? wv_t : wr_t));
  const int n0 = (rblk & 7) * 128, m0 = (rblk >> 3) * 128;
  const int tid = threadIdx.x, lane = tid & 63, w = tid >> 6;
  const int wm = w >> 1, wn = w & 1, g = lane >> 4, lc = lane & 15;
  const int arow = tid >> 1, acol = (tid & 1) * 16;  // A staging role: 16 f32/thread

  f32x4 acc[4][4] = {};
  float4 pa0, pa1, pa2, pa3;
  // prologue: stage tile 0
#pragma unroll
  for (int s = 0; s < 2; ++s) {
    int cch = s * 256 + tid;
    int row = cch >> 2, ko = (cch & 3) * 8;
    gload16(&Bt[(size_t)(n0 + row) * 1024 + ko], &sB[0][(s * 256 + w * 64) * 8]);
  }
  {
    const float* ap = &Af[(size_t)(m0 + arow) * 1024 + acol];
    pa0 = *(const float4*)&ap[0];
    pa1 = *(const float4*)&ap[4];
    pa2 = *(const float4*)&ap[8];
    pa3 = *(const float4*)&ap[12];
    us8v lo, hi;
    lo[0] = f2bf(pa0.x); lo[1] = f2bf(pa0.y); lo[2] = f2bf(pa0.z); lo[3] = f2bf(pa0.w);
    lo[4] = f2bf(pa1.x); lo[5] = f2bf(pa1.y); lo[6] = f2bf(pa1.z); lo[7] = f2bf(pa1.w);
    hi[0] = f2bf(pa2.x); hi[1] = f2bf(pa2.y); hi[2] = f2bf(pa2.z); hi[3] = f2bf(pa2.w);
    hi[4] = f2bf(pa3.x); hi[5] = f2bf(pa3.y); hi[6] = f2bf(pa3.z); hi[7] = f2bf(pa3.w);
    *(us8v*)&sA[0][arow * 32 + acol] = lo;
    *(us8v*)&sA[0][arow * 32 + acol + 8] = hi;
  }
  __syncthreads();

  int c = 0;
  for (int kt = 0; kt < 1024; kt += 32) {
    const int cn = c ^ 1;
    if (kt < 992) {
#pragma unroll
      for (int s = 0; s < 2; ++s) {
        int cch = s * 256 + tid;
        int row = cch >> 2, ko = (cch & 3) * 8;
        gload16(&Bt[(size_t)(n0 + row) * 1024 + kt + 32 + ko], &sB[cn][(s * 256 + w * 64) * 8]);
      }
      const float* ap = &Af[(size_t)(m0 + arow) * 1024 + kt + 32 + acol];
      pa0 = *(const float4*)&ap[0];
      pa1 = *(const float4*)&ap[4];
      pa2 = *(const float4*)&ap[8];
      pa3 = *(const float4*)&ap[12];
    }
    // compute current tile
    bf16x8 af[4], bfr[4];
#pragma unroll
    for (int i = 0; i < 4; ++i) {
      af[i] = *(const bf16x8*)&sA[c][(wm * 64 + i * 16 + lc) * 32 + g * 8];
      bfr[i] = *(const bf16x8*)&sB[c][(wn * 64 + i * 16 + lc) * 32 + g * 8];
    }
#pragma unroll
    for (int mi = 0; mi < 4; ++mi)
#pragma unroll
      for (int ni = 0; ni < 4; ++ni)
        acc[mi][ni] = mfma16(af[mi], bfr[ni], acc[mi][ni]);
    if (kt < 992) {
      us8v lo, hi;
      lo[0] = f2bf(pa0.x); lo[1] = f2bf(pa0.y); lo[2] = f2bf(pa0.z); lo[3] = f2bf(pa0.w);
      lo[4] = f2bf(pa1.x); lo[5] = f2bf(pa1.y); lo[6] = f2bf(pa1.z); lo[7] = f2bf(pa1.w);
      hi[0] = f2bf(pa2.x); hi[1] = f2bf(pa2.y); hi[2] = f2bf(pa2.z); hi[3] = f2bf(pa2.w);
      hi[4] = f2bf(pa3.x); hi[5] = f2bf(pa3.y); hi[6] = f2bf(pa3.z); hi[7] = f2bf(pa3.w);
      *(us8v*)&sA[cn][arow * 32 + acol] = lo;
      *(us8v*)&sA[cn][arow * 32 + acol + 8] = hi;
    }
    __syncthreads();
    c = cn;
  }

#pragma unroll
  for (int ni = 0; ni < 4; ++ni) {
    int col = n0 + wn * 64 + ni * 16 + lc;
    float bw = 0.f, br = 0.f, bs = 0.f;
    if (sel == 0) { bw = rwb[col]; br = rrb[col]; bs = rsb[col]; }
#pragma unroll
    for (int mi = 0; mi < 4; ++mi) {
      int rowb = m0 + wm * 64 + mi * 16 + g * 4;
#pragma unroll
      for (int r = 0; r < 4; ++r) {
        float v = acc[mi][ni][r];
        size_t idx = (size_t)(rowb + r) * 1024 + col;
        if (sel == 0) {
          qwb[idx] = f2bf((v + bw) * 0.125f);
          qrb[idx] = f2bf((v + br) * 0.125f);
          qsb[idx] = f2bf((v + bs) * 0.125f);
        } else if (sel == 1) {
          khb[idx] = f2bf(v);
        } else if (sel == 2) {
          vhb[idx] = f2bf(v);
        } else {
          krhb[idx] = f2bf(v);
        }
      }
    }
  }
}

// ---------------- out-projection: BM=64, 2-phase dbuf, f32 B reg-staged ----------------
__global__ __launch_bounds__(256) void gemm64_out(const unsigned short* __restrict__ A,
                                                  const float* __restrict__ Bf,
                                                  float* __restrict__ C) {
  __shared__ unsigned short sA[2][64 * 32];
  __shared__ unsigned short sB[2][128 * 32];
  const int tid = threadIdx.x, lane = tid & 63, w = tid >> 6;
  const int wm = w >> 1, wn = w & 1, g = lane >> 4, lc = lane & 15;
  const int m0 = blockIdx.y * 64, n0 = blockIdx.x * 128;
  const int arow = tid >> 2, ako = (tid & 3) * 8;
  const int brow = tid >> 1, bcol = (tid & 1) * 16;
  f32x4 acc[2][4] = {};
  float4 pb0, pb1, pb2, pb3;
  // prologue
  gload16(&A[(size_t)(m0 + arow) * 1024 + ako], &sA[0][w * 512]);
  {
    const float* bp = &Bf[(size_t)(n0 + brow) * 1024 + bcol];
    pb0 = *(const float4*)&bp[0];
    pb1 = *(const float4*)&bp[4];
    pb2 = *(const float4*)&bp[8];
    pb3 = *(const float4*)&bp[12];
    us8v lo, hi;
    lo[0] = f2bf(pb0.x); lo[1] = f2bf(pb0.y); lo[2] = f2bf(pb0.z); lo[3] = f2bf(pb0.w);
    lo[4] = f2bf(pb1.x); lo[5] = f2bf(pb1.y); lo[6] = f2bf(pb1.z); lo[7] = f2bf(pb1.w);
    hi[0] = f2bf(pb2.x); hi[1] = f2bf(pb2.y); hi[2] = f2bf(pb2.z); hi[3] = f2bf(pb2.w);
    hi[4] = f2bf(pb3.x); hi[5] = f2bf(pb3.y); hi[6] = f2bf(pb3.z); hi[7] = f2bf(pb3.w);
    *(us8v*)&sB[0][brow * 32 + bcol] = lo;
    *(us8v*)&sB[0][brow * 32 + bcol + 8] = hi;
  }
  __syncthreads();

  int c = 0;
  for (int kt = 0; kt < 1024; kt += 32) {
    const int cn = c ^ 1;
    if (kt < 992) {
      gload16(&A[(size_t)(m0 + arow) * 1024 + kt + 32 + ako], &sA[cn][w * 512]);
      const float* bp = &Bf[(size_t)(n0 + brow) * 1024 + kt + 32 + bcol];
      pb0 = *(const float4*)&bp[0];
      pb1 = *(const float4*)&bp[4];
      pb2 = *(const float4*)&bp[8];
      pb3 = *(const float4*)&bp[12];
    }
    bf16x8 af[2], bfr[4];
#pragma unroll
    for (int i = 0; i < 2; ++i)
      af[i] = *(const bf16x8*)&sA[c][(wm * 32 + i * 16 + lc) * 32 + g * 8];
#pragma unroll
    for (int i = 0; i < 4; ++i)
      bfr[i] = *(const bf16x8*)&sB[c][(wn * 64 + i * 16 + lc) * 32 + g * 8];
#pragma unroll
    for (int mi = 0; mi < 2; ++mi)
#pragma unroll
      for (int ni = 0; ni < 4; ++ni)
        acc[mi][ni] = mfma16(af[mi], bfr[ni], acc[mi][ni]);
    if (kt < 992) {
      us8v lo, hi;
      lo[0] = f2bf(pb0.x); lo[1] = f2bf(pb0.y); lo[2] = f2bf(pb0.z); lo[3] = f2bf(pb0.w);
      lo[4] = f2bf(pb1.x); lo[5] = f2bf(pb1.y); lo[6] = f2bf(pb1.z); lo[7] = f2bf(pb1.w);
      hi[0] = f2bf(pb2.x); hi[1] = f2bf(pb2.y); hi[2] = f2bf(pb2.z); hi[3] = f2bf(pb2.w);
      hi[4] = f2bf(pb3.x); hi[5] = f2bf(pb3.y); hi[6] = f2bf(pb3.z); hi[7] = f2bf(pb3.w);
      *(us8v*)&sB[cn][brow * 32 + bcol] = lo;
      *(us8v*)&sB[cn][brow * 32 + bcol + 8] = hi;
    }
    __syncthreads();
    c = cn;
  }
#pragma unroll
  for (int ni = 0; ni < 4; ++ni) {
    int col = n0 + wn * 64 + ni * 16 + lc;
#pragma unroll
    for (int mi = 0; mi < 2; ++mi) {
      int rowb = m0 + wm * 32 + mi * 16 + g * 4;
#pragma unroll
      for (int r = 0; r < 4; ++r)
        C[(size_t)(rowb + r) * 1024 + col] = acc[mi][ni][r];
    }
  }
}

// ---------------- V transpose ----------------
__global__ __launch_bounds__(256) void transpose_v(const unsigned short* __restrict__ vh,
                                                   unsigned short* __restrict__ vT) {
  __shared__ unsigned short t[64][65];
  const int bn = blockIdx.y, j0 = blockIdx.x * 64;
  const int b = bn >> 4, n = bn & 15;
  const int r = threadIdx.x >> 4;
  const int c4 = (threadIdx.x & 15) * 4;
#pragma unroll
  for (int s = 0; s < 4; ++s) {
    int j = r + s * 16;
    us4 v = *(const us4*)&vh[((size_t)(j0 + j) * 2 + b) * 1024 + n * 64 + c4];
    t[j][c4 + 0] = v[0]; t[j][c4 + 1] = v[1]; t[j][c4 + 2] = v[2]; t[j][c4 + 3] = v[3];
  }
  __syncthreads();
#pragma unroll
  for (int s = 0; s < 4; ++s) {
    int d = r + s * 16;
    us4 v;
    v[0] = t[c4 + 0][d]; v[1] = t[c4 + 1][d]; v[2] = t[c4 + 2][d]; v[3] = t[c4 + 3][d];
    *(us4*)&vT[((size_t)bn * 64 + d) * 1024 + j0 + c4] = v;
  }
}

// ---------------- ef0/ef1 per (i,b,n) ----------------
__global__ __launch_bounds__(256) void ef_kernel(const unsigned short* __restrict__ qs,
                                                 const float* __restrict__ seg_embed,
                                                 float* __restrict__ ef0, float* __restrict__ ef1) {
  int gw = blockIdx.x * 4 + (threadIdx.x >> 6);
  int lane = threadIdx.x & 63;
  int n = gw & 15, ib = gw >> 4;
  int i = ib >> 1, b = ib & 1;
  float qv = bf2f(qs[(size_t)ib * 1024 + n * 64 + lane]);
  float p0 = qv * seg_embed[n * 64 + lane];
  float p1 = qv * seg_embed[1024 + n * 64 + lane];
#pragma unroll
  for (int m = 1; m < 64; m <<= 1) {
    p0 += __shfl_xor(p0, m);
    p1 += __shfl_xor(p1, m);
  }
  if (lane == 0) {
    ef0[(b * 16 + n) * 1024 + i] = p0;
    ef1[(b * 16 + n) * 1024 + i] = p1;
  }
}

// ---------------- fused relative attention: BI=128, 8 waves, j-split x2 ----------------
__global__ __launch_bounds__(512, 4) void attn_kernel(
    const unsigned short* __restrict__ qw, const unsigned short* __restrict__ qr,
    const unsigned short* __restrict__ kh, const unsigned short* __restrict__ krh,
    const unsigned short* __restrict__ vT,
    const float* __restrict__ ef0, const float* __restrict__ ef1,
    const unsigned int* __restrict__ segmask,
    float* __restrict__ part, float* __restrict__ ml) {
  __shared__ unsigned short sK[64][72];
  __shared__ unsigned short sVT[64][72];
  __shared__ unsigned short sKR[256][72];  // circular band, slot = jr & 255
  __shared__ unsigned short sP[8][16][80];

  const int tid = threadIdx.x, lane = tid & 63, w = tid >> 6;  // w: 0..7
  const int g = lane >> 4, lc = lane & 15;
  const int bn = blockIdx.x, b = bn >> 4, n = bn & 15;
  const int i0 = blockIdx.y * 128;
  const int js = blockIdx.z;
  const int S0 = 1024 + js * 512 - i0 - 127;

  bf16x8 fqw[2], fqr[2];
  const int qrow = i0 + w * 16 + lc;
#pragma unroll
  for (int ks = 0; ks < 2; ++ks) {
    size_t off = ((size_t)qrow * 2 + b) * 1024 + n * 64 + ks * 32 + g * 8;
    fqw[ks] = *(const bf16x8*)&qw[off];
    fqr[ks] = *(const bf16x8*)&qr[off];
  }
  float ef0v[4], dv[4];
  unsigned int smoff[4];
#pragma unroll
  for (int r = 0; r < 4; ++r) {
    int i = i0 + w * 16 + g * 4 + r;
    float e0 = ef0[bn * 1024 + i];
    ef0v[r] = e0;
    dv[r] = ef1[bn * 1024 + i] - e0;
    smoff[r] = ((unsigned)b << 20) | ((unsigned)i << 10) | (unsigned)lc;
  }
  float mrun[4], lsum[4];
  f32x4 accO[4] = {};
#pragma unroll
  for (int r = 0; r < 4; ++r) { mrun[r] = -3e38f; lsum[r] = 0.f; }

  const int srow = tid >> 3;
  const int sko = (tid & 7) * 8;

#pragma unroll
  for (int pp = 0; pp < 3; ++pp) {
    int jr = S0 + pp * 64 + srow;
    *(uint4*)&sKR[jr & 255][sko] =
        *(const uint4*)&krh[((size_t)jr * 2 + b) * 1024 + n * 64 + sko];
  }
  int j0 = js * 512;
  uint4 rK = *(const uint4*)&kh[((size_t)(j0 + srow) * 2 + b) * 1024 + n * 64 + sko];
  uint4 rV = *(const uint4*)&vT[((size_t)bn * 64 + srow) * 1024 + j0 + sko];
  uint4 rR = *(const uint4*)&krh[((size_t)(S0 + 192 + srow) * 2 + b) * 1024 + n * 64 + sko];

  for (int t = 0; t < 8; ++t) {
    j0 = (js * 8 + t) * 64;
    __syncthreads();
    *(uint4*)&sK[srow][sko] = rK;
    *(uint4*)&sVT[srow][sko] = rV;
    if (t < 7) {
      *(uint4*)&sKR[(S0 + 192 + t * 64 + srow) & 255][sko] = rR;
      int j0n = j0 + 64;
      rK = *(const uint4*)&kh[((size_t)(j0n + srow) * 2 + b) * 1024 + n * 64 + sko];
      rV = *(const uint4*)&vT[((size_t)bn * 64 + srow) * 1024 + j0n + sko];
      if (t < 6) {
        int jr = S0 + 256 + t * 64 + srow;
        if (jr > 2047) jr = 2047;
        rR = *(const uint4*)&krh[((size_t)jr * 2 + b) * 1024 + n * 64 + sko];
      }
    }
    unsigned int msv[4][4];
#pragma unroll
    for (int r = 0; r < 4; ++r)
#pragma unroll
      for (int nf = 0; nf < 4; ++nf)
        msv[r][nf] = segmask[smoff[r] + j0 + nf * 16];
    __syncthreads();

    const int base = S0 + t * 64 + (7 - w) * 16;
    f32x4 bdk[5];
#pragma unroll
    for (int k = 0; k < 5; ++k) {
      f32x4 a = {0.f, 0.f, 0.f, 0.f};
#pragma unroll
      for (int ks = 0; ks < 2; ++ks) {
        bf16x8 fk = *(const bf16x8*)&sKR[(base + k * 16 + lc) & 255][ks * 32 + g * 8];
        a = mfma16(fqr[ks], fk, a);
      }
      bdk[k] = a;
    }
    float p[4][4];
#pragma unroll
    for (int r = 0; r < 4; ++r) {
      const int a_ = g * 4 + r;
      const int srcl = (lane & 48) | ((lc + 15 - a_) & 15);
      float s0 = __shfl(bdk[0][r], srcl);
      float s1 = __shfl(bdk[1][r], srcl);
      float s2 = __shfl(bdk[2][r], srcl);
      float s3 = __shfl(bdk[3][r], srcl);
      float s4 = __shfl(bdk[4][r], srcl);
      const bool lo = lc <= a_;
#pragma unroll
      for (int nf = 0; nf < 4; ++nf) {
        unsigned int u = msv[r][nf];
        float sgv = bf2f((unsigned short)(u & 0xffffu));
        float mkv = bf2f((unsigned short)(u >> 16));
        float bdv = lo ? (nf == 0 ? s0 : nf == 1 ? s1 : nf == 2 ? s2 : s3)
                       : (nf == 0 ? s1 : nf == 1 ? s2 : nf == 2 ? s3 : s4);
        p[r][nf] = ef0v[r] + sgv * dv[r] + mkv + bdv;
      }
    }
    f32x4 aa[4];
#pragma unroll
    for (int nf = 0; nf < 4; ++nf) {
      f32x4 a = {0.f, 0.f, 0.f, 0.f};
#pragma unroll
      for (int ks = 0; ks < 2; ++ks) {
        bf16x8 fk = *(const bf16x8*)&sK[nf * 16 + lc][ks * 32 + g * 8];
        a = mfma16(fqw[ks], fk, a);
      }
      aa[nf] = a;
    }
#pragma unroll
    for (int r = 0; r < 4; ++r)
#pragma unroll
      for (int nf = 0; nf < 4; ++nf) p[r][nf] += aa[nf][r];

#pragma unroll
    for (int r = 0; r < 4; ++r) {
      float mt = fmaxf(fmaxf(p[r][0], p[r][1]), fmaxf(p[r][2], p[r][3]));
      mt = rmax16(mt);
      float mnew = fmaxf(mrun[r], mt);
      float corr = __expf(mrun[r] - mnew);
      mrun[r] = mnew;
      float se = 0.f;
#pragma unroll
      for (int nf = 0; nf < 4; ++nf) {
        float e = __expf(p[r][nf] - mnew);
        p[r][nf] = e;
        se += e;
      }
      se = rsum16(se);
      lsum[r] = lsum[r] * corr + se;
#pragma unroll
      for (int df = 0; df < 4; ++df) accO[df][r] *= corr;
#pragma unroll
      for (int nf = 0; nf < 4; ++nf)
        sP[w][g * 4 + r][nf * 16 + lc] = f2bf(p[r][nf]);
    }
#pragma unroll
    for (int ks = 0; ks < 2; ++ks) {
      bf16x8 fp = *(const bf16x8*)&sP[w][lc][ks * 32 + g * 8];
#pragma unroll
      for (int df = 0; df < 4; ++df) {
        bf16x8 fv = *(const bf16x8*)&sVT[df * 16 + lc][ks * 32 + g * 8];
        accO[df] = mfma16(fp, fv, accO[df]);
      }
    }
  }
#pragma unroll
  for (int r = 0; r < 4; ++r) {
    int i = i0 + w * 16 + g * 4 + r;
    size_t pb = ((size_t)(js * 32 + bn) * 1024 + i) * 64;
#pragma unroll
    for (int df = 0; df < 4; ++df) part[pb + df * 16 + lc] = accO[df][r];
    if (lc == 0) {
      size_t mb = (((size_t)js * 32 + bn) * 1024 + i) * 2;
      ml[mb] = mrun[r];
      ml[mb + 1] = lsum[r];
    }
  }
}

// ---------------- combine the two j-splits ----------------
__global__ __launch_bounds__(256) void combine_kernel(const float* __restrict__ part,
                                                      const float* __restrict__ ml,
                                                      unsigned short* __restrict__ av) {
  int gw = blockIdx.x * 4 + (threadIdx.x >> 6);
  int lane = threadIdx.x & 63;
  int bn = gw >> 10, i = gw & 1023;
  int b = bn >> 4, n = bn & 15;
  float m0 = ml[((size_t)bn * 1024 + i) * 2];
  float l0 = ml[((size_t)bn * 1024 + i) * 2 + 1];
  float m1 = ml[(((size_t)32 + bn) * 1024 + i) * 2];
  float l1 = ml[(((size_t)32 + bn) * 1024 + i) * 2 + 1];
  float mx = fmaxf(m0, m1);
  float w0 = __expf(m0 - mx), w1 = __expf(m1 - mx);
  float inv = 1.f / (l0 * w0 + l1 * w1);
  float o = part[((size_t)bn * 1024 + i) * 64 + lane] * w0 +
            part[(((size_t)32 + bn) * 1024 + i) * 64 + lane] * w1;
  av[((size_t)i * 2 + b) * 1024 + n * 64 + lane] = f2bf(o * inv);
}

// ---------------- residual + LayerNorm ----------------
__global__ __launch_bounds__(256) void ln_kernel(const float* __restrict__ gout,
                                                 const float* __restrict__ h,
                                                 const float* __restrict__ gamma,
                                                 const float* __restrict__ beta,
                                                 float* __restrict__ out) {
  __shared__ float red[8];
  const int row = blockIdx.x;
  const int tid = threadIdx.x;
  float x[4];
  float s = 0.f;
#pragma unroll
  for (int q = 0; q < 4; ++q) {
    int d = tid + q * 256;
    x[q] = gout[(size_t)row * 1024 + d] + h[(size_t)row * 1024 + d];
    s += x[q];
  }
#pragma unroll
  for (int m = 1; m < 64; m <<= 1) s += __shfl_xor(s, m);
  if ((tid & 63) == 0) red[tid >> 6] = s;
  __syncthreads();
  s = red[0] + red[1] + red[2] + red[3];
  float mu = s * (1.f / 1024.f);
  float v = 0.f;
#pragma unroll
  for (int q = 0; q < 4; ++q) {
    float dd = x[q] - mu;
    v += dd * dd;
  }
#pragma unroll
  for (int m = 1; m < 64; m <<= 1) v += __shfl_xor(v, m);
  if ((tid & 63) == 0) red[4 + (tid >> 6)] = v;
  __syncthreads();
  v = red[4] + red[5] + red[6] + red[7];
  float rstd = rsqrtf(v * (1.f / 1024.f) + 1e-12f);
#pragma unroll
  for (int q = 0; q < 4; ++q) {
    int d = tid + q * 256;
    out[(size_t)row * 1024 + d] = (x[q] - mu) * rstd * gamma[d] + beta[d];
  }
}

extern "C" void kernel_launch(void* const* d_in, const int* in_sizes, int n_in,
                              void* d_out, int out_size, void* d_ws, size_t ws_size,
                              hipStream_t stream) {
  const float* h = (const float*)d_in[0];
  const float* r = (const float*)d_in[1];
  const unsigned char* seg = (const unsigned char*)d_in[2];
  const float* mask = (const float*)d_in[3];
  const float* wq = (const float*)d_in[4];
  const float* wk = (const float*)d_in[5];
  const float* wv = (const float*)d_in[6];
  const float* wr = (const float*)d_in[7];
  const float* wo = (const float*)d_in[8];
  const float* rwb = (const float*)d_in[9];
  const float* rrb = (const float*)d_in[10];
  const float* rsb = (const float*)d_in[11];
  const float* seg_embed = (const float*)d_in[12];
  const float* gamma = (const float*)d_in[13];
  const float* beta = (const float*)d_in[14];
  float* out = (float*)d_out;

  char* ws = (char*)d_ws;
  size_t off = 0;
  auto alloc = [&](size_t bytes) {
    size_t cur = off;
    off = (off + bytes + 255) & ~(size_t)255;
    return cur;
  };
  unsigned short* wq_t = (unsigned short*)(ws + alloc(1024 * 1024 * 2));
  unsigned short* wk_t = (unsigned short*)(ws + alloc(1024 * 1024 * 2));
  unsigned short* wv_t = (unsigned short*)(ws + alloc(1024 * 1024 * 2));
  unsigned short* wr_t = (unsigned short*)(ws + alloc(1024 * 1024 * 2));
  unsigned short* qwb = (unsigned short*)(ws + alloc(2048 * 1024 * 2));
  unsigned short* qrb = (unsigned short*)(ws + alloc(2048 * 1024 * 2));
  unsigned short* qsb = (unsigned short*)(ws + alloc(2048 * 1024 * 2));
  unsigned short* khb = (unsigned short*)(ws + alloc(2048 * 1024 * 2));
  unsigned short* vhb = (unsigned short*)(ws + alloc(2048 * 1024 * 2));
  unsigned short* krhb = (unsigned short*)(ws + alloc(4096 * 1024 * 2));
  unsigned short* vTb = (unsigned short*)(ws + alloc(2048 * 1024 * 2));
  float* ef0 = (float*)(ws + alloc(2048 * 16 * 4));
  float* ef1 = (float*)(ws + alloc(2048 * 16 * 4));
  unsigned int* segmask = (unsigned int*)(ws + alloc(2 * 1024 * 1024 * 4));
  unsigned short* avb = (unsigned short*)(ws + alloc(2048 * 1024 * 2));
  float* gout = (float*)(ws + alloc(2048 * 1024 * 4));
  float* part = (float*)(ws + alloc((size_t)2 * 32 * 1024 * 64 * 4));
  float* mlb = (float*)(ws + alloc((size_t)2 * 32 * 1024 * 2 * 4));
  (void)ws_size; (void)in_sizes; (void)n_in; (void)out_size;

  transpose_cast4<<<dim3(32, 32, 4), 256, 0, stream>>>(wq, wk, wv, wr, wq_t, wk_t, wv_t, wr_t);
  segmask_kernel<<<4096, 256, 0, stream>>>(seg, mask, segmask);

  proj4_kernel<<<640, 256, 0, stream>>>(h, r, wq_t, wk_t, wv_t, wr_t, rwb, rrb, rsb,
                                        qwb, qrb, qsb, khb, vhb, krhb);

  transpose_v<<<dim3(16, 32), 256, 0, stream>>>(vhb, vTb);
  ef_kernel<<<8192, 256, 0, stream>>>(qsb, seg_embed, ef0, ef1);

  attn_kernel<<<dim3(32, 8, 2), 512, 0, stream>>>(qwb, qrb, khb, krhb, vTb,
                                                  ef0, ef1, segmask, part, mlb);
  combine_kernel<<<8192, 256, 0, stream>>>(part, mlb, avb);

  gemm64_out<<<dim3(8, 32), 256, 0, stream>>>(avb, wo, gout);
  ln_kernel<<<2048, 256, 0, stream>>>(gout, h, gamma, beta, out);
}

// Round 5
// 154.148 us; speedup vs baseline: 1.1826x; 1.1826x over previous
//
#include <hip/hip_runtime.h>

typedef __bf16 bf16x8 __attribute__((ext_vector_type(8)));
typedef float f32x4 __attribute__((ext_vector_type(4)));
typedef unsigned short us4 __attribute__((ext_vector_type(4)));

__device__ __forceinline__ unsigned short f2bf(float f) {
  unsigned int u = __builtin_bit_cast(unsigned int, f);
  u += 0x7fffu + ((u >> 16) & 1u);
  return (unsigned short)(u >> 16);
}
__device__ __forceinline__ float bf2f(unsigned short s) {
  unsigned int u = ((unsigned int)s) << 16;
  return __builtin_bit_cast(float, u);
}
__device__ __forceinline__ f32x4 mfma16(bf16x8 a, bf16x8 b, f32x4 c) {
  return __builtin_amdgcn_mfma_f32_16x16x32_bf16(a, b, c, 0, 0, 0);
}
__device__ __forceinline__ void gload16(const void* g, void* l) {
  __builtin_amdgcn_global_load_lds(
      (const __attribute__((address_space(1))) unsigned int*)g,
      (__attribute__((address_space(3))) unsigned int*)l, 16, 0, 0);
}
template <int CTRL>
__device__ __forceinline__ float dppf(float x) {
  return __builtin_bit_cast(
      float, __builtin_amdgcn_mov_dpp(__builtin_bit_cast(int, x), CTRL, 0xf, 0xf, true));
}
__device__ __forceinline__ float rmax16(float x) {
  x = fmaxf(x, dppf<0xB1>(x));
  x = fmaxf(x, dppf<0x4E>(x));
  x = fmaxf(x, dppf<0x124>(x));
  x = fmaxf(x, dppf<0x128>(x));
  return x;
}
__device__ __forceinline__ float rsum16(float x) {
  x += dppf<0xB1>(x);
  x += dppf<0x4E>(x);
  x += dppf<0x124>(x);
  x += dppf<0x128>(x);
  return x;
}

// ---------------- fused cast f32 -> bf16 for h, r, wo ----------------
__global__ __launch_bounds__(256) void cast3_kernel(
    const float* __restrict__ h, const float* __restrict__ r, const float* __restrict__ wo,
    unsigned short* __restrict__ hb, unsigned short* __restrict__ rb,
    unsigned short* __restrict__ wo_b) {
  int idx = blockIdx.x * 256 + threadIdx.x;  // float4 index
  const float* in;
  unsigned short* out;
  int o;
  if (idx < 524288) { in = h; out = hb; o = idx; }
  else if (idx < 1572864) { in = r; out = rb; o = idx - 524288; }
  else { in = wo; out = wo_b; o = idx - 1572864; }
  float4 v = ((const float4*)in)[o];
  us4 t;
  t[0] = f2bf(v.x); t[1] = f2bf(v.y); t[2] = f2bf(v.z); t[3] = f2bf(v.w);
  *(us4*)&out[o * 4] = t;
}

// ---------------- transpose+cast 4 weights [1024][1024] f32 -> [N][K] bf16 ----------------
__global__ __launch_bounds__(256) void transpose_cast4(
    const float* __restrict__ w0, const float* __restrict__ w1,
    const float* __restrict__ w2, const float* __restrict__ w3,
    unsigned short* __restrict__ o0, unsigned short* __restrict__ o1,
    unsigned short* __restrict__ o2, unsigned short* __restrict__ o3) {
  __shared__ float t[32][33];
  const int z = blockIdx.z;
  const float* in = z == 0 ? w0 : (z == 1 ? w1 : (z == 2 ? w2 : w3));
  unsigned short* out = z == 0 ? o0 : (z == 1 ? o1 : (z == 2 ? o2 : o3));
  int k0 = blockIdx.y * 32;
  int n0 = blockIdx.x * 32;
  int r = threadIdx.x >> 5;
  int c = threadIdx.x & 31;
#pragma unroll
  for (int s = 0; s < 4; ++s)
    t[r + s * 8][c] = in[(k0 + r + s * 8) * 1024 + n0 + c];
  __syncthreads();
#pragma unroll
  for (int s = 0; s < 4; ++s)
    out[(n0 + r + s * 8) * 1024 + k0 + c] = f2bf(t[c][r + s * 8]);
}

// ---------------- segmask: pack {bf16(-1e30*mask), bf16(seg)} per (b,i,j) ----------------
__global__ __launch_bounds__(256) void segmask_kernel(const unsigned char* __restrict__ seg,
                                                      const float* __restrict__ mask,
                                                      unsigned int* __restrict__ out) {
  int ij = blockIdx.x * 256 + threadIdx.x;
  unsigned short sv = *(const unsigned short*)&seg[ij * 2];
  float2 mv = *(const float2*)&mask[(size_t)ij * 2];
  unsigned int o0 = ((unsigned int)f2bf(mv.x * -1e30f) << 16) | ((sv & 0xffu) ? 0x3f80u : 0u);
  unsigned int o1 = ((unsigned int)f2bf(mv.y * -1e30f) << 16) | ((sv >> 8) ? 0x3f80u : 0u);
  out[ij] = o0;
  out[1048576 + ij] = o1;
}

// ---------------- GEMM core: 128x128 tile, BK=64, swizzled LDS (src-preswz + swz read) ----------------
__device__ __forceinline__ void gemm_core128(const unsigned short* __restrict__ A,
                                             const unsigned short* __restrict__ Bt,
                                             int m0, int n0,
                                             unsigned short* sA, unsigned short* sB,
                                             int tid, f32x4 (&acc)[4][4]) {
  const int lane = tid & 63, w = tid >> 6;
  const int wm = w >> 1, wn = w & 1, g = lane >> 4, lc = lane & 15;
  for (int kt = 0; kt < 1024; kt += 64) {
    __syncthreads();
#pragma unroll
    for (int s = 0; s < 4; ++s) {
      int c = s * 256 + tid;
      int row = c >> 3;
      // linear LDS dest slot (c&7); fetch the XOR-permuted global slot so a
      // swizzled READ (slot ^ row&7) is conflict-free (both-sides rule).
      int ko = (((c & 7) ^ (row & 7))) * 8;
      int lbase = (s * 256 + w * 64) * 8;  // shorts; wave-uniform, +lane*16B implicit
      gload16(&A[(size_t)(m0 + row) * 1024 + kt + ko], &sA[lbase]);
      gload16(&Bt[(size_t)(n0 + row) * 1024 + kt + ko], &sB[lbase]);
    }
    __syncthreads();
    bf16x8 af[4][2], bfr[4][2];
#pragma unroll
    for (int i = 0; i < 4; ++i) {
#pragma unroll
      for (int ks = 0; ks < 2; ++ks) {
        int ra = wm * 64 + i * 16 + lc;
        int rb = wn * 64 + i * 16 + lc;
        af[i][ks] = *(const bf16x8*)&sA[ra * 64 + (((ks * 4 + g) ^ (ra & 7)) * 8)];
        bfr[i][ks] = *(const bf16x8*)&sB[rb * 64 + (((ks * 4 + g) ^ (rb & 7)) * 8)];
      }
    }
#pragma unroll
    for (int ks = 0; ks < 2; ++ks)
#pragma unroll
      for (int mi = 0; mi < 4; ++mi)
#pragma unroll
        for (int ni = 0; ni < 4; ++ni)
          acc[mi][ni] = mfma16(af[mi][ks], bfr[ni][ks], acc[mi][ni]);
  }
}

// ---------------- all 4 projections in one launch ----------------
__global__ __launch_bounds__(256) void proj4_kernel(
    const unsigned short* __restrict__ hb, const unsigned short* __restrict__ rb,
    const unsigned short* __restrict__ wq_t, const unsigned short* __restrict__ wk_t,
    const unsigned short* __restrict__ wv_t, const unsigned short* __restrict__ wr_t,
    const float* __restrict__ rwb, const float* __restrict__ rrb, const float* __restrict__ rsb,
    unsigned short* __restrict__ qwb, unsigned short* __restrict__ qrb,
    unsigned short* __restrict__ qsb,
    unsigned short* __restrict__ khb, unsigned short* __restrict__ vhb,
    unsigned short* __restrict__ krhb) {
  __shared__ unsigned short sA[128 * 64];
  __shared__ unsigned short sB[128 * 64];
  const int bx = blockIdx.x;
  int sel, rblk;
  const unsigned short* A;
  if (bx < 384) { sel = bx >> 7; rblk = bx & 127; A = hb; }
  else { sel = 3; rblk = bx - 384; A = rb; }
  const unsigned short* Bt = sel == 0 ? wq_t : (sel == 1 ? wk_t : (sel == 2 ? wv_t : wr_t));
  const int n0 = (rblk & 7) * 128, m0 = (rblk >> 3) * 128;
  const int tid = threadIdx.x, lane = tid & 63, w = tid >> 6;
  const int wm = w >> 1, wn = w & 1, g = lane >> 4, lc = lane & 15;
  f32x4 acc[4][4] = {};
  gemm_core128(A, Bt, m0, n0, sA, sB, tid, acc);
#pragma unroll
  for (int ni = 0; ni < 4; ++ni) {
    int col = n0 + wn * 64 + ni * 16 + lc;
    float bw = 0.f, br = 0.f, bs = 0.f;
    if (sel == 0) { bw = rwb[col]; br = rrb[col]; bs = rsb[col]; }
#pragma unroll
    for (int mi = 0; mi < 4; ++mi) {
      int rowb = m0 + wm * 64 + mi * 16 + g * 4;
#pragma unroll
      for (int r = 0; r < 4; ++r) {
        float v = acc[mi][ni][r];
        size_t idx = (size_t)(rowb + r) * 1024 + col;
        if (sel == 0) {
          qwb[idx] = f2bf((v + bw) * 0.125f);
          qrb[idx] = f2bf((v + br) * 0.125f);
          qsb[idx] = f2bf((v + bs) * 0.125f);
        } else if (sel == 1) {
          khb[idx] = f2bf(v);
        } else if (sel == 2) {
          vhb[idx] = f2bf(v);
        } else {
          krhb[idx] = f2bf(v);
        }
      }
    }
  }
}

// ---------------- out-projection: BM=64 tile (R3 form) ----------------
__global__ __launch_bounds__(256) void gemm64_out(const unsigned short* __restrict__ A,
                                                  const unsigned short* __restrict__ Bt,
                                                  float* __restrict__ C) {
  __shared__ unsigned short sA[64 * 32];
  __shared__ unsigned short sB[128 * 32];
  const int tid = threadIdx.x, lane = tid & 63, w = tid >> 6;
  const int wm = w >> 1, wn = w & 1, g = lane >> 4, lc = lane & 15;
  const int m0 = blockIdx.y * 64, n0 = blockIdx.x * 128;
  f32x4 acc[2][4] = {};
  for (int kt = 0; kt < 1024; kt += 32) {
    __syncthreads();
    {
      int c = tid;
      gload16(&A[(size_t)(m0 + (c >> 2)) * 1024 + kt + (c & 3) * 8], &sA[w * 64 * 8]);
      gload16(&Bt[(size_t)(n0 + (c >> 2)) * 1024 + kt + (c & 3) * 8], &sB[w * 64 * 8]);
      int c2 = tid + 256;
      gload16(&Bt[(size_t)(n0 + (c2 >> 2)) * 1024 + kt + (c2 & 3) * 8], &sB[(256 + w * 64) * 8]);
    }
    __syncthreads();
    bf16x8 af[2], bfr[4];
#pragma unroll
    for (int i = 0; i < 2; ++i)
      af[i] = *(const bf16x8*)&sA[(wm * 32 + i * 16 + lc) * 32 + g * 8];
#pragma unroll
    for (int i = 0; i < 4; ++i)
      bfr[i] = *(const bf16x8*)&sB[(wn * 64 + i * 16 + lc) * 32 + g * 8];
#pragma unroll
    for (int mi = 0; mi < 2; ++mi)
#pragma unroll
      for (int ni = 0; ni < 4; ++ni)
        acc[mi][ni] = mfma16(af[mi], bfr[ni], acc[mi][ni]);
  }
#pragma unroll
  for (int ni = 0; ni < 4; ++ni) {
    int col = n0 + wn * 64 + ni * 16 + lc;
#pragma unroll
    for (int mi = 0; mi < 2; ++mi) {
      int rowb = m0 + wm * 32 + mi * 16 + g * 4;
#pragma unroll
      for (int r = 0; r < 4; ++r)
        C[(size_t)(rowb + r) * 1024 + col] = acc[mi][ni][r];
    }
  }
}

// ---------------- V transpose ----------------
__global__ __launch_bounds__(256) void transpose_v(const unsigned short* __restrict__ vh,
                                                   unsigned short* __restrict__ vT) {
  __shared__ unsigned short t[64][65];
  const int bn = blockIdx.y, j0 = blockIdx.x * 64;
  const int b = bn >> 4, n = bn & 15;
  const int r = threadIdx.x >> 4;
  const int c4 = (threadIdx.x & 15) * 4;
#pragma unroll
  for (int s = 0; s < 4; ++s) {
    int j = r + s * 16;
    us4 v = *(const us4*)&vh[((size_t)(j0 + j) * 2 + b) * 1024 + n * 64 + c4];
    t[j][c4 + 0] = v[0]; t[j][c4 + 1] = v[1]; t[j][c4 + 2] = v[2]; t[j][c4 + 3] = v[3];
  }
  __syncthreads();
#pragma unroll
  for (int s = 0; s < 4; ++s) {
    int d = r + s * 16;
    us4 v;
    v[0] = t[c4 + 0][d]; v[1] = t[c4 + 1][d]; v[2] = t[c4 + 2][d]; v[3] = t[c4 + 3][d];
    *(us4*)&vT[((size_t)bn * 64 + d) * 1024 + j0 + c4] = v;
  }
}

// ---------------- ef0/ef1 per (i,b,n) ----------------
__global__ __launch_bounds__(256) void ef_kernel(const unsigned short* __restrict__ qs,
                                                 const float* __restrict__ seg_embed,
                                                 float* __restrict__ ef0, float* __restrict__ ef1) {
  int gw = blockIdx.x * 4 + (threadIdx.x >> 6);
  int lane = threadIdx.x & 63;
  int n = gw & 15, ib = gw >> 4;
  int i = ib >> 1, b = ib & 1;
  float qv = bf2f(qs[(size_t)ib * 1024 + n * 64 + lane]);
  float p0 = qv * seg_embed[n * 64 + lane];
  float p1 = qv * seg_embed[1024 + n * 64 + lane];
#pragma unroll
  for (int m = 1; m < 64; m <<= 1) {
    p0 += __shfl_xor(p0, m);
    p1 += __shfl_xor(p1, m);
  }
  if (lane == 0) {
    ef0[(b * 16 + n) * 1024 + i] = p0;
    ef1[(b * 16 + n) * 1024 + i] = p1;
  }
}

// ---------------- fused relative attention: BI=128, 8 waves, j-split x2 ----------------
__global__ __launch_bounds__(512, 4) void attn_kernel(
    const unsigned short* __restrict__ qw, const unsigned short* __restrict__ qr,
    const unsigned short* __restrict__ kh, const unsigned short* __restrict__ krh,
    const unsigned short* __restrict__ vT,
    const float* __restrict__ ef0, const float* __restrict__ ef1,
    const unsigned int* __restrict__ segmask,
    float* __restrict__ part, float* __restrict__ ml) {
  __shared__ unsigned short sK[64][72];
  __shared__ unsigned short sVT[64][72];
  __shared__ unsigned short sKR[256][72];  // circular band, slot = jr & 255
  __shared__ unsigned short sP[8][16][80];

  const int tid = threadIdx.x, lane = tid & 63, w = tid >> 6;  // w: 0..7
  const int g = lane >> 4, lc = lane & 15;
  const int bn = blockIdx.x, b = bn >> 4, n = bn & 15;
  const int i0 = blockIdx.y * 128;
  const int js = blockIdx.z;
  const int S0 = 1024 + js * 512 - i0 - 127;

  bf16x8 fqw[2], fqr[2];
  const int qrow = i0 + w * 16 + lc;
#pragma unroll
  for (int ks = 0; ks < 2; ++ks) {
    size_t off = ((size_t)qrow * 2 + b) * 1024 + n * 64 + ks * 32 + g * 8;
    fqw[ks] = *(const bf16x8*)&qw[off];
    fqr[ks] = *(const bf16x8*)&qr[off];
  }
  float ef0v[4], dv[4];
  unsigned int smoff[4];
#pragma unroll
  for (int r = 0; r < 4; ++r) {
    int i = i0 + w * 16 + g * 4 + r;
    float e0 = ef0[bn * 1024 + i];
    ef0v[r] = e0;
    dv[r] = ef1[bn * 1024 + i] - e0;
    smoff[r] = ((unsigned)b << 20) | ((unsigned)i << 10) | (unsigned)lc;
  }
  float mrun[4], lsum[4];
  f32x4 accO[4] = {};
#pragma unroll
  for (int r = 0; r < 4; ++r) { mrun[r] = -3e38f; lsum[r] = 0.f; }

  const int srow = tid >> 3;
  const int sko = (tid & 7) * 8;

#pragma unroll
  for (int pp = 0; pp < 3; ++pp) {
    int jr = S0 + pp * 64 + srow;
    *(uint4*)&sKR[jr & 255][sko] =
        *(const uint4*)&krh[((size_t)jr * 2 + b) * 1024 + n * 64 + sko];
  }
  int j0 = js * 512;
  uint4 rK = *(const uint4*)&kh[((size_t)(j0 + srow) * 2 + b) * 1024 + n * 64 + sko];
  uint4 rV = *(const uint4*)&vT[((size_t)bn * 64 + srow) * 1024 + j0 + sko];
  uint4 rR = *(const uint4*)&krh[((size_t)(S0 + 192 + srow) * 2 + b) * 1024 + n * 64 + sko];

  for (int t = 0; t < 8; ++t) {
    j0 = (js * 8 + t) * 64;
    __syncthreads();
    *(uint4*)&sK[srow][sko] = rK;
    *(uint4*)&sVT[srow][sko] = rV;
    if (t < 7) {
      *(uint4*)&sKR[(S0 + 192 + t * 64 + srow) & 255][sko] = rR;
      int j0n = j0 + 64;
      rK = *(const uint4*)&kh[((size_t)(j0n + srow) * 2 + b) * 1024 + n * 64 + sko];
      rV = *(const uint4*)&vT[((size_t)bn * 64 + srow) * 1024 + j0n + sko];
      if (t < 6) {
        int jr = S0 + 256 + t * 64 + srow;
        if (jr > 2047) jr = 2047;
        rR = *(const uint4*)&krh[((size_t)jr * 2 + b) * 1024 + n * 64 + sko];
      }
    }
    unsigned int msv[4][4];
#pragma unroll
    for (int r = 0; r < 4; ++r)
#pragma unroll
      for (int nf = 0; nf < 4; ++nf)
        msv[r][nf] = segmask[smoff[r] + j0 + nf * 16];
    __syncthreads();

    const int base = S0 + t * 64 + (7 - w) * 16;
    f32x4 bdk[5];
#pragma unroll
    for (int k = 0; k < 5; ++k) {
      f32x4 a = {0.f, 0.f, 0.f, 0.f};
#pragma unroll
      for (int ks = 0; ks < 2; ++ks) {
        bf16x8 fk = *(const bf16x8*)&sKR[(base + k * 16 + lc) & 255][ks * 32 + g * 8];
        a = mfma16(fqr[ks], fk, a);
      }
      bdk[k] = a;
    }
    float p[4][4];
#pragma unroll
    for (int r = 0; r < 4; ++r) {
      const int a_ = g * 4 + r;
      const int srcl = (lane & 48) | ((lc + 15 - a_) & 15);
      float s0 = __shfl(bdk[0][r], srcl);
      float s1 = __shfl(bdk[1][r], srcl);
      float s2 = __shfl(bdk[2][r], srcl);
      float s3 = __shfl(bdk[3][r], srcl);
      float s4 = __shfl(bdk[4][r], srcl);
      const bool lo = lc <= a_;
#pragma unroll
      for (int nf = 0; nf < 4; ++nf) {
        unsigned int u = msv[r][nf];
        float sgv = bf2f((unsigned short)(u & 0xffffu));
        float mkv = bf2f((unsigned short)(u >> 16));
        float bdv = lo ? (nf == 0 ? s0 : nf == 1 ? s1 : nf == 2 ? s2 : s3)
                       : (nf == 0 ? s1 : nf == 1 ? s2 : nf == 2 ? s3 : s4);
        p[r][nf] = ef0v[r] + sgv * dv[r] + mkv + bdv;
      }
    }
    f32x4 aa[4];
#pragma unroll
    for (int nf = 0; nf < 4; ++nf) {
      f32x4 a = {0.f, 0.f, 0.f, 0.f};
#pragma unroll
      for (int ks = 0; ks < 2; ++ks) {
        bf16x8 fk = *(const bf16x8*)&sK[nf * 16 + lc][ks * 32 + g * 8];
        a = mfma16(fqw[ks], fk, a);
      }
      aa[nf] = a;
    }
#pragma unroll
    for (int r = 0; r < 4; ++r)
#pragma unroll
      for (int nf = 0; nf < 4; ++nf) p[r][nf] += aa[nf][r];

#pragma unroll
    for (int r = 0; r < 4; ++r) {
      float mt = fmaxf(fmaxf(p[r][0], p[r][1]), fmaxf(p[r][2], p[r][3]));
      mt = rmax16(mt);
      float mnew = fmaxf(mrun[r], mt);
      float corr = __expf(mrun[r] - mnew);
      mrun[r] = mnew;
      float se = 0.f;
#pragma unroll
      for (int nf = 0; nf < 4; ++nf) {
        float e = __expf(p[r][nf] - mnew);
        p[r][nf] = e;
        se += e;
      }
      se = rsum16(se);
      lsum[r] = lsum[r] * corr + se;
#pragma unroll
      for (int df = 0; df < 4; ++df) accO[df][r] *= corr;
#pragma unroll
      for (int nf = 0; nf < 4; ++nf)
        sP[w][g * 4 + r][nf * 16 + lc] = f2bf(p[r][nf]);
    }
#pragma unroll
    for (int ks = 0; ks < 2; ++ks) {
      bf16x8 fp = *(const bf16x8*)&sP[w][lc][ks * 32 + g * 8];
#pragma unroll
      for (int df = 0; df < 4; ++df) {
        bf16x8 fv = *(const bf16x8*)&sVT[df * 16 + lc][ks * 32 + g * 8];
        accO[df] = mfma16(fp, fv, accO[df]);
      }
    }
  }
#pragma unroll
  for (int r = 0; r < 4; ++r) {
    int i = i0 + w * 16 + g * 4 + r;
    size_t pb = ((size_t)(js * 32 + bn) * 1024 + i) * 64;
#pragma unroll
    for (int df = 0; df < 4; ++df) part[pb + df * 16 + lc] = accO[df][r];
    if (lc == 0) {
      size_t mb = (((size_t)js * 32 + bn) * 1024 + i) * 2;
      ml[mb] = mrun[r];
      ml[mb + 1] = lsum[r];
    }
  }
}

// ---------------- combine the two j-splits ----------------
__global__ __launch_bounds__(256) void combine_kernel(const float* __restrict__ part,
                                                      const float* __restrict__ ml,
                                                      unsigned short* __restrict__ av) {
  int gw = blockIdx.x * 4 + (threadIdx.x >> 6);
  int lane = threadIdx.x & 63;
  int bn = gw >> 10, i = gw & 1023;
  int b = bn >> 4, n = bn & 15;
  float m0 = ml[((size_t)bn * 1024 + i) * 2];
  float l0 = ml[((size_t)bn * 1024 + i) * 2 + 1];
  float m1 = ml[(((size_t)32 + bn) * 1024 + i) * 2];
  float l1 = ml[(((size_t)32 + bn) * 1024 + i) * 2 + 1];
  float mx = fmaxf(m0, m1);
  float w0 = __expf(m0 - mx), w1 = __expf(m1 - mx);
  float inv = 1.f / (l0 * w0 + l1 * w1);
  float o = part[((size_t)bn * 1024 + i) * 64 + lane] * w0 +
            part[(((size_t)32 + bn) * 1024 + i) * 64 + lane] * w1;
  av[((size_t)i * 2 + b) * 1024 + n * 64 + lane] = f2bf(o * inv);
}

// ---------------- residual + LayerNorm ----------------
__global__ __launch_bounds__(256) void ln_kernel(const float* __restrict__ gout,
                                                 const float* __restrict__ h,
                                                 const float* __restrict__ gamma,
                                                 const float* __restrict__ beta,
                                                 float* __restrict__ out) {
  __shared__ float red[8];
  const int row = blockIdx.x;
  const int tid = threadIdx.x;
  float x[4];
  float s = 0.f;
#pragma unroll
  for (int q = 0; q < 4; ++q) {
    int d = tid + q * 256;
    x[q] = gout[(size_t)row * 1024 + d] + h[(size_t)row * 1024 + d];
    s += x[q];
  }
#pragma unroll
  for (int m = 1; m < 64; m <<= 1) s += __shfl_xor(s, m);
  if ((tid & 63) == 0) red[tid >> 6] = s;
  __syncthreads();
  s = red[0] + red[1] + red[2] + red[3];
  float mu = s * (1.f / 1024.f);
  float v = 0.f;
#pragma unroll
  for (int q = 0; q < 4; ++q) {
    float dd = x[q] - mu;
    v += dd * dd;
  }
#pragma unroll
  for (int m = 1; m < 64; m <<= 1) v += __shfl_xor(v, m);
  if ((tid & 63) == 0) red[4 + (tid >> 6)] = v;
  __syncthreads();
  v = red[4] + red[5] + red[6] + red[7];
  float rstd = rsqrtf(v * (1.f / 1024.f) + 1e-12f);
#pragma unroll
  for (int q = 0; q < 4; ++q) {
    int d = tid + q * 256;
    out[(size_t)row * 1024 + d] = (x[q] - mu) * rstd * gamma[d] + beta[d];
  }
}

extern "C" void kernel_launch(void* const* d_in, const int* in_sizes, int n_in,
                              void* d_out, int out_size, void* d_ws, size_t ws_size,
                              hipStream_t stream) {
  const float* h = (const float*)d_in[0];
  const float* r = (const float*)d_in[1];
  const unsigned char* seg = (const unsigned char*)d_in[2];
  const float* mask = (const float*)d_in[3];
  const float* wq = (const float*)d_in[4];
  const float* wk = (const float*)d_in[5];
  const float* wv = (const float*)d_in[6];
  const float* wr = (const float*)d_in[7];
  const float* wo = (const float*)d_in[8];
  const float* rwb = (const float*)d_in[9];
  const float* rrb = (const float*)d_in[10];
  const float* rsb = (const float*)d_in[11];
  const float* seg_embed = (const float*)d_in[12];
  const float* gamma = (const float*)d_in[13];
  const float* beta = (const float*)d_in[14];
  float* out = (float*)d_out;

  char* ws = (char*)d_ws;
  size_t off = 0;
  auto alloc = [&](size_t bytes) {
    size_t cur = off;
    off = (off + bytes + 255) & ~(size_t)255;
    return cur;
  };
  unsigned short* hb = (unsigned short*)(ws + alloc(2048 * 1024 * 2));
  unsigned short* rb = (unsigned short*)(ws + alloc(4096 * 1024 * 2));
  unsigned short* wq_t = (unsigned short*)(ws + alloc(1024 * 1024 * 2));
  unsigned short* wk_t = (unsigned short*)(ws + alloc(1024 * 1024 * 2));
  unsigned short* wv_t = (unsigned short*)(ws + alloc(1024 * 1024 * 2));
  unsigned short* wr_t = (unsigned short*)(ws + alloc(1024 * 1024 * 2));
  unsigned short* wo_b = (unsigned short*)(ws + alloc(1024 * 1024 * 2));
  unsigned short* qwb = (unsigned short*)(ws + alloc(2048 * 1024 * 2));
  unsigned short* qrb = (unsigned short*)(ws + alloc(2048 * 1024 * 2));
  unsigned short* qsb = (unsigned short*)(ws + alloc(2048 * 1024 * 2));
  unsigned short* khb = (unsigned short*)(ws + alloc(2048 * 1024 * 2));
  unsigned short* vhb = (unsigned short*)(ws + alloc(2048 * 1024 * 2));
  unsigned short* krhb = (unsigned short*)(ws + alloc(4096 * 1024 * 2));
  unsigned short* vTb = (unsigned short*)(ws + alloc(2048 * 1024 * 2));
  float* ef0 = (float*)(ws + alloc(2048 * 16 * 4));
  float* ef1 = (float*)(ws + alloc(2048 * 16 * 4));
  unsigned int* segmask = (unsigned int*)(ws + alloc(2 * 1024 * 1024 * 4));
  unsigned short* avb = (unsigned short*)(ws + alloc(2048 * 1024 * 2));
  float* gout = (float*)(ws + alloc(2048 * 1024 * 4));
  float* part = (float*)(ws + alloc((size_t)2 * 32 * 1024 * 64 * 4));
  float* mlb = (float*)(ws + alloc((size_t)2 * 32 * 1024 * 2 * 4));
  (void)ws_size; (void)in_sizes; (void)n_in; (void)out_size;

  cast3_kernel<<<7168, 256, 0, stream>>>(h, r, wo, hb, rb, wo_b);
  transpose_cast4<<<dim3(32, 32, 4), 256, 0, stream>>>(wq, wk, wv, wr, wq_t, wk_t, wv_t, wr_t);
  segmask_kernel<<<4096, 256, 0, stream>>>(seg, mask, segmask);

  proj4_kernel<<<640, 256, 0, stream>>>(hb, rb, wq_t, wk_t, wv_t, wr_t, rwb, rrb, rsb,
                                        qwb, qrb, qsb, khb, vhb, krhb);

  transpose_v<<<dim3(16, 32), 256, 0, stream>>>(vhb, vTb);
  ef_kernel<<<8192, 256, 0, stream>>>(qsb, seg_embed, ef0, ef1);

  attn_kernel<<<dim3(32, 8, 2), 512, 0, stream>>>(qwb, qrb, khb, krhb, vTb,
                                                  ef0, ef1, segmask, part, mlb);
  combine_kernel<<<8192, 256, 0, stream>>>(part, mlb, avb);

  gemm64_out<<<dim3(8, 32), 256, 0, stream>>>(avb, wo_b, gout);
  ln_kernel<<<2048, 256, 0, stream>>>(gout, h, gamma, beta, out);
}

// Round 6
// 148.561 us; speedup vs baseline: 1.2271x; 1.0376x over previous
//
#include <hip/hip_runtime.h>

typedef __bf16 bf16x8 __attribute__((ext_vector_type(8)));
typedef float f32x4 __attribute__((ext_vector_type(4)));
typedef unsigned short us4 __attribute__((ext_vector_type(4)));

__device__ __forceinline__ unsigned short f2bf(float f) {
  unsigned int u = __builtin_bit_cast(unsigned int, f);
  u += 0x7fffu + ((u >> 16) & 1u);
  return (unsigned short)(u >> 16);
}
__device__ __forceinline__ float bf2f(unsigned short s) {
  unsigned int u = ((unsigned int)s) << 16;
  return __builtin_bit_cast(float, u);
}
__device__ __forceinline__ f32x4 mfma16(bf16x8 a, bf16x8 b, f32x4 c) {
  return __builtin_amdgcn_mfma_f32_16x16x32_bf16(a, b, c, 0, 0, 0);
}
__device__ __forceinline__ void gload16(const void* g, void* l) {
  __builtin_amdgcn_global_load_lds(
      (const __attribute__((address_space(1))) unsigned int*)g,
      (__attribute__((address_space(3))) unsigned int*)l, 16, 0, 0);
}
template <int CTRL>
__device__ __forceinline__ float dppf(float x) {
  return __builtin_bit_cast(
      float, __builtin_amdgcn_mov_dpp(__builtin_bit_cast(int, x), CTRL, 0xf, 0xf, true));
}
__device__ __forceinline__ float rmax16(float x) {
  x = fmaxf(x, dppf<0xB1>(x));
  x = fmaxf(x, dppf<0x4E>(x));
  x = fmaxf(x, dppf<0x124>(x));
  x = fmaxf(x, dppf<0x128>(x));
  return x;
}
__device__ __forceinline__ float rsum16(float x) {
  x += dppf<0xB1>(x);
  x += dppf<0x4E>(x);
  x += dppf<0x124>(x);
  x += dppf<0x128>(x);
  return x;
}

// ---------------- fused cast f32 -> bf16 for h, r, wo ----------------
__global__ __launch_bounds__(256) void cast3_kernel(
    const float* __restrict__ h, const float* __restrict__ r, const float* __restrict__ wo,
    unsigned short* __restrict__ hb, unsigned short* __restrict__ rb,
    unsigned short* __restrict__ wo_b) {
  int idx = blockIdx.x * 256 + threadIdx.x;  // float4 index
  const float* in;
  unsigned short* out;
  int o;
  if (idx < 524288) { in = h; out = hb; o = idx; }
  else if (idx < 1572864) { in = r; out = rb; o = idx - 524288; }
  else { in = wo; out = wo_b; o = idx - 1572864; }
  float4 v = ((const float4*)in)[o];
  us4 t;
  t[0] = f2bf(v.x); t[1] = f2bf(v.y); t[2] = f2bf(v.z); t[3] = f2bf(v.w);
  *(us4*)&out[o * 4] = t;
}

// ---------------- transpose+cast 4 weights [1024][1024] f32 -> [N][K] bf16 ----------------
__global__ __launch_bounds__(256) void transpose_cast4(
    const float* __restrict__ w0, const float* __restrict__ w1,
    const float* __restrict__ w2, const float* __restrict__ w3,
    unsigned short* __restrict__ o0, unsigned short* __restrict__ o1,
    unsigned short* __restrict__ o2, unsigned short* __restrict__ o3) {
  __shared__ float t[32][33];
  const int z = blockIdx.z;
  const float* in = z == 0 ? w0 : (z == 1 ? w1 : (z == 2 ? w2 : w3));
  unsigned short* out = z == 0 ? o0 : (z == 1 ? o1 : (z == 2 ? o2 : o3));
  int k0 = blockIdx.y * 32;
  int n0 = blockIdx.x * 32;
  int r = threadIdx.x >> 5;
  int c = threadIdx.x & 31;
#pragma unroll
  for (int s = 0; s < 4; ++s)
    t[r + s * 8][c] = in[(k0 + r + s * 8) * 1024 + n0 + c];
  __syncthreads();
#pragma unroll
  for (int s = 0; s < 4; ++s)
    out[(n0 + r + s * 8) * 1024 + k0 + c] = f2bf(t[c][r + s * 8]);
}

// ---------------- segmask: pack {bf16(-1e30*mask), bf16(seg)} per (b,i,j) ----------------
__global__ __launch_bounds__(256) void segmask_kernel(const unsigned char* __restrict__ seg,
                                                      const float* __restrict__ mask,
                                                      unsigned int* __restrict__ out) {
  int ij = blockIdx.x * 256 + threadIdx.x;
  unsigned short sv = *(const unsigned short*)&seg[ij * 2];
  float2 mv = *(const float2*)&mask[(size_t)ij * 2];
  unsigned int o0 = ((unsigned int)f2bf(mv.x * -1e30f) << 16) | ((sv & 0xffu) ? 0x3f80u : 0u);
  unsigned int o1 = ((unsigned int)f2bf(mv.y * -1e30f) << 16) | ((sv >> 8) ? 0x3f80u : 0u);
  out[ij] = o0;
  out[1048576 + ij] = o1;
}

// ---------------- all 4 projections: 128x128 tile, BK=64, 2-phase dbuf, swizzled LDS ----------------
__global__ __launch_bounds__(256) void proj4_kernel(
    const unsigned short* __restrict__ hb, const unsigned short* __restrict__ rb,
    const unsigned short* __restrict__ wq_t, const unsigned short* __restrict__ wk_t,
    const unsigned short* __restrict__ wv_t, const unsigned short* __restrict__ wr_t,
    const float* __restrict__ rwb, const float* __restrict__ rrb, const float* __restrict__ rsb,
    unsigned short* __restrict__ qwb, unsigned short* __restrict__ qrb,
    unsigned short* __restrict__ qsb,
    unsigned short* __restrict__ khb, unsigned short* __restrict__ vhb,
    unsigned short* __restrict__ krhb) {
  __shared__ unsigned short sA[2][128 * 64];
  __shared__ unsigned short sB[2][128 * 64];
  const int bx = blockIdx.x;
  int sel, rblk;
  const unsigned short* A;
  if (bx < 384) { sel = bx >> 7; rblk = bx & 127; A = hb; }
  else { sel = 3; rblk = bx - 384; A = rb; }
  const unsigned short* Bt = sel == 0 ? wq_t : (sel == 1 ? wk_t : (sel == 2 ? wv_t : wr_t));
  const int n0 = (rblk & 7) * 128, m0 = (rblk >> 3) * 128;
  const int tid = threadIdx.x, lane = tid & 63, w = tid >> 6;
  const int wm = w >> 1, wn = w & 1, g = lane >> 4, lc = lane & 15;

  f32x4 acc[4][4] = {};

  auto STAGE = [&](int buf, int kt) {
#pragma unroll
    for (int s = 0; s < 4; ++s) {
      int c = s * 256 + tid;
      int row = c >> 3;
      // linear LDS dest; fetch XOR-permuted global slot so swizzled READ is conflict-free
      int ko = ((c & 7) ^ (row & 7)) * 8;
      int lbase = (s * 256 + w * 64) * 8;
      gload16(&A[(size_t)(m0 + row) * 1024 + kt + ko], &sA[buf][lbase]);
      gload16(&Bt[(size_t)(n0 + row) * 1024 + kt + ko], &sB[buf][lbase]);
    }
  };

  STAGE(0, 0);
  __syncthreads();

  for (int kt = 0; kt < 1024; kt += 64) {
    const int cur = (kt >> 6) & 1;
    if (kt < 960) STAGE(cur ^ 1, kt + 64);
    bf16x8 af[4][2], bfr[4][2];
#pragma unroll
    for (int i = 0; i < 4; ++i) {
#pragma unroll
      for (int ks = 0; ks < 2; ++ks) {
        int ra = wm * 64 + i * 16 + lc;
        int rb_ = wn * 64 + i * 16 + lc;
        af[i][ks] = *(const bf16x8*)&sA[cur][ra * 64 + (((ks * 4 + g) ^ (ra & 7)) * 8)];
        bfr[i][ks] = *(const bf16x8*)&sB[cur][rb_ * 64 + (((ks * 4 + g) ^ (rb_ & 7)) * 8)];
      }
    }
#pragma unroll
    for (int ks = 0; ks < 2; ++ks)
#pragma unroll
      for (int mi = 0; mi < 4; ++mi)
#pragma unroll
        for (int ni = 0; ni < 4; ++ni)
          acc[mi][ni] = mfma16(af[mi][ks], bfr[ni][ks], acc[mi][ni]);
    __syncthreads();
  }

#pragma unroll
  for (int ni = 0; ni < 4; ++ni) {
    int col = n0 + wn * 64 + ni * 16 + lc;
    float bw = 0.f, br = 0.f, bs = 0.f;
    if (sel == 0) { bw = rwb[col]; br = rrb[col]; bs = rsb[col]; }
#pragma unroll
    for (int mi = 0; mi < 4; ++mi) {
      int rowb = m0 + wm * 64 + mi * 16 + g * 4;
#pragma unroll
      for (int r = 0; r < 4; ++r) {
        float v = acc[mi][ni][r];
        size_t idx = (size_t)(rowb + r) * 1024 + col;
        if (sel == 0) {
          qwb[idx] = f2bf((v + bw) * 0.125f);
          qrb[idx] = f2bf((v + br) * 0.125f);
          qsb[idx] = f2bf((v + bs) * 0.125f);
        } else if (sel == 1) {
          khb[idx] = f2bf(v);
        } else if (sel == 2) {
          vhb[idx] = f2bf(v);
        } else {
          krhb[idx] = f2bf(v);
        }
      }
    }
  }
}

// ---------------- out-projection: 64x128 tile, BK=64, 2-phase dbuf, swizzled LDS ----------------
__global__ __launch_bounds__(256) void gemm64_out(const unsigned short* __restrict__ A,
                                                  const unsigned short* __restrict__ Bt,
                                                  float* __restrict__ C) {
  __shared__ unsigned short sA[2][64 * 64];
  __shared__ unsigned short sB[2][128 * 64];
  const int tid = threadIdx.x, lane = tid & 63, w = tid >> 6;
  const int wm = w >> 1, wn = w & 1, g = lane >> 4, lc = lane & 15;
  const int m0 = blockIdx.y * 64, n0 = blockIdx.x * 128;
  f32x4 acc[2][4] = {};

  auto STAGE = [&](int buf, int kt) {
#pragma unroll
    for (int s = 0; s < 2; ++s) {
      int c = s * 256 + tid;
      int row = c >> 3;
      int ko = ((c & 7) ^ (row & 7)) * 8;
      gload16(&A[(size_t)(m0 + row) * 1024 + kt + ko], &sA[buf][(s * 256 + w * 64) * 8]);
    }
#pragma unroll
    for (int s = 0; s < 4; ++s) {
      int c = s * 256 + tid;
      int row = c >> 3;
      int ko = ((c & 7) ^ (row & 7)) * 8;
      gload16(&Bt[(size_t)(n0 + row) * 1024 + kt + ko], &sB[buf][(s * 256 + w * 64) * 8]);
    }
  };

  STAGE(0, 0);
  __syncthreads();

  for (int kt = 0; kt < 1024; kt += 64) {
    const int cur = (kt >> 6) & 1;
    if (kt < 960) STAGE(cur ^ 1, kt + 64);
    bf16x8 af[2][2], bfr[4][2];
#pragma unroll
    for (int ks = 0; ks < 2; ++ks) {
#pragma unroll
      for (int i = 0; i < 2; ++i) {
        int ra = wm * 32 + i * 16 + lc;
        af[i][ks] = *(const bf16x8*)&sA[cur][ra * 64 + (((ks * 4 + g) ^ (ra & 7)) * 8)];
      }
#pragma unroll
      for (int i = 0; i < 4; ++i) {
        int rb_ = wn * 64 + i * 16 + lc;
        bfr[i][ks] = *(const bf16x8*)&sB[cur][rb_ * 64 + (((ks * 4 + g) ^ (rb_ & 7)) * 8)];
      }
    }
#pragma unroll
    for (int ks = 0; ks < 2; ++ks)
#pragma unroll
      for (int mi = 0; mi < 2; ++mi)
#pragma unroll
        for (int ni = 0; ni < 4; ++ni)
          acc[mi][ni] = mfma16(af[mi][ks], bfr[ni][ks], acc[mi][ni]);
    __syncthreads();
  }
#pragma unroll
  for (int ni = 0; ni < 4; ++ni) {
    int col = n0 + wn * 64 + ni * 16 + lc;
#pragma unroll
    for (int mi = 0; mi < 2; ++mi) {
      int rowb = m0 + wm * 32 + mi * 16 + g * 4;
#pragma unroll
      for (int r = 0; r < 4; ++r)
        C[(size_t)(rowb + r) * 1024 + col] = acc[mi][ni][r];
    }
  }
}

// ---------------- V transpose ----------------
__global__ __launch_bounds__(256) void transpose_v(const unsigned short* __restrict__ vh,
                                                   unsigned short* __restrict__ vT) {
  __shared__ unsigned short t[64][65];
  const int bn = blockIdx.y, j0 = blockIdx.x * 64;
  const int b = bn >> 4, n = bn & 15;
  const int r = threadIdx.x >> 4;
  const int c4 = (threadIdx.x & 15) * 4;
#pragma unroll
  for (int s = 0; s < 4; ++s) {
    int j = r + s * 16;
    us4 v = *(const us4*)&vh[((size_t)(j0 + j) * 2 + b) * 1024 + n * 64 + c4];
    t[j][c4 + 0] = v[0]; t[j][c4 + 1] = v[1]; t[j][c4 + 2] = v[2]; t[j][c4 + 3] = v[3];
  }
  __syncthreads();
#pragma unroll
  for (int s = 0; s < 4; ++s) {
    int d = r + s * 16;
    us4 v;
    v[0] = t[c4 + 0][d]; v[1] = t[c4 + 1][d]; v[2] = t[c4 + 2][d]; v[3] = t[c4 + 3][d];
    *(us4*)&vT[((size_t)bn * 64 + d) * 1024 + j0 + c4] = v;
  }
}

// ---------------- ef0/ef1 per (i,b,n) ----------------
__global__ __launch_bounds__(256) void ef_kernel(const unsigned short* __restrict__ qs,
                                                 const float* __restrict__ seg_embed,
                                                 float* __restrict__ ef0, float* __restrict__ ef1) {
  int gw = blockIdx.x * 4 + (threadIdx.x >> 6);
  int lane = threadIdx.x & 63;
  int n = gw & 15, ib = gw >> 4;
  int i = ib >> 1, b = ib & 1;
  float qv = bf2f(qs[(size_t)ib * 1024 + n * 64 + lane]);
  float p0 = qv * seg_embed[n * 64 + lane];
  float p1 = qv * seg_embed[1024 + n * 64 + lane];
#pragma unroll
  for (int m = 1; m < 64; m <<= 1) {
    p0 += __shfl_xor(p0, m);
    p1 += __shfl_xor(p1, m);
  }
  if (lane == 0) {
    ef0[(b * 16 + n) * 1024 + i] = p0;
    ef1[(b * 16 + n) * 1024 + i] = p1;
  }
}

// ---------------- fused relative attention: BI=128, 8 waves, j-split x2 ----------------
__global__ __launch_bounds__(512, 4) void attn_kernel(
    const unsigned short* __restrict__ qw, const unsigned short* __restrict__ qr,
    const unsigned short* __restrict__ kh, const unsigned short* __restrict__ krh,
    const unsigned short* __restrict__ vT,
    const float* __restrict__ ef0, const float* __restrict__ ef1,
    const unsigned int* __restrict__ segmask,
    float* __restrict__ part, float* __restrict__ ml) {
  __shared__ unsigned short sK[64][72];
  __shared__ unsigned short sVT[64][72];
  __shared__ unsigned short sKR[256][72];  // circular band, slot = jr & 255
  __shared__ unsigned short sP[8][16][80];

  const int tid = threadIdx.x, lane = tid & 63, w = tid >> 6;  // w: 0..7
  const int g = lane >> 4, lc = lane & 15;
  const int bn = blockIdx.x, b = bn >> 4, n = bn & 15;
  const int i0 = blockIdx.y * 128;
  const int js = blockIdx.z;
  const int S0 = 1024 + js * 512 - i0 - 127;

  bf16x8 fqw[2], fqr[2];
  const int qrow = i0 + w * 16 + lc;
#pragma unroll
  for (int ks = 0; ks < 2; ++ks) {
    size_t off = ((size_t)qrow * 2 + b) * 1024 + n * 64 + ks * 32 + g * 8;
    fqw[ks] = *(const bf16x8*)&qw[off];
    fqr[ks] = *(const bf16x8*)&qr[off];
  }
  float ef0v[4], dv[4];
  unsigned int smoff[4];
#pragma unroll
  for (int r = 0; r < 4; ++r) {
    int i = i0 + w * 16 + g * 4 + r;
    float e0 = ef0[bn * 1024 + i];
    ef0v[r] = e0;
    dv[r] = ef1[bn * 1024 + i] - e0;
    smoff[r] = ((unsigned)b << 20) | ((unsigned)i << 10) | (unsigned)lc;
  }
  float mrun[4], lsum[4];
  f32x4 accO[4] = {};
#pragma unroll
  for (int r = 0; r < 4; ++r) { mrun[r] = -3e38f; lsum[r] = 0.f; }

  const int srow = tid >> 3;
  const int sko = (tid & 7) * 8;

#pragma unroll
  for (int pp = 0; pp < 3; ++pp) {
    int jr = S0 + pp * 64 + srow;
    *(uint4*)&sKR[jr & 255][sko] =
        *(const uint4*)&krh[((size_t)jr * 2 + b) * 1024 + n * 64 + sko];
  }
  int j0 = js * 512;
  uint4 rK = *(const uint4*)&kh[((size_t)(j0 + srow) * 2 + b) * 1024 + n * 64 + sko];
  uint4 rV = *(const uint4*)&vT[((size_t)bn * 64 + srow) * 1024 + j0 + sko];
  uint4 rR = *(const uint4*)&krh[((size_t)(S0 + 192 + srow) * 2 + b) * 1024 + n * 64 + sko];

  for (int t = 0; t < 8; ++t) {
    j0 = (js * 8 + t) * 64;
    __syncthreads();
    *(uint4*)&sK[srow][sko] = rK;
    *(uint4*)&sVT[srow][sko] = rV;
    if (t < 7) {
      *(uint4*)&sKR[(S0 + 192 + t * 64 + srow) & 255][sko] = rR;
      int j0n = j0 + 64;
      rK = *(const uint4*)&kh[((size_t)(j0n + srow) * 2 + b) * 1024 + n * 64 + sko];
      rV = *(const uint4*)&vT[((size_t)bn * 64 + srow) * 1024 + j0n + sko];
      if (t < 6) {
        int jr = S0 + 256 + t * 64 + srow;
        if (jr > 2047) jr = 2047;
        rR = *(const uint4*)&krh[((size_t)jr * 2 + b) * 1024 + n * 64 + sko];
      }
    }
    unsigned int msv[4][4];
#pragma unroll
    for (int r = 0; r < 4; ++r)
#pragma unroll
      for (int nf = 0; nf < 4; ++nf)
        msv[r][nf] = segmask[smoff[r] + j0 + nf * 16];
    __syncthreads();

    const int base = S0 + t * 64 + (7 - w) * 16;
    f32x4 bdk[5];
#pragma unroll
    for (int k = 0; k < 5; ++k) {
      f32x4 a = {0.f, 0.f, 0.f, 0.f};
#pragma unroll
      for (int ks = 0; ks < 2; ++ks) {
        bf16x8 fk = *(const bf16x8*)&sKR[(base + k * 16 + lc) & 255][ks * 32 + g * 8];
        a = mfma16(fqr[ks], fk, a);
      }
      bdk[k] = a;
    }
    float p[4][4];
#pragma unroll
    for (int r = 0; r < 4; ++r) {
      const int a_ = g * 4 + r;
      const int srcl = (lane & 48) | ((lc + 15 - a_) & 15);
      float s0 = __shfl(bdk[0][r], srcl);
      float s1 = __shfl(bdk[1][r], srcl);
      float s2 = __shfl(bdk[2][r], srcl);
      float s3 = __shfl(bdk[3][r], srcl);
      float s4 = __shfl(bdk[4][r], srcl);
      const bool lo = lc <= a_;
#pragma unroll
      for (int nf = 0; nf < 4; ++nf) {
        unsigned int u = msv[r][nf];
        float sgv = bf2f((unsigned short)(u & 0xffffu));
        float mkv = bf2f((unsigned short)(u >> 16));
        float bdv = lo ? (nf == 0 ? s0 : nf == 1 ? s1 : nf == 2 ? s2 : s3)
                       : (nf == 0 ? s1 : nf == 1 ? s2 : nf == 2 ? s3 : s4);
        p[r][nf] = ef0v[r] + sgv * dv[r] + mkv + bdv;
      }
    }
    f32x4 aa[4];
#pragma unroll
    for (int nf = 0; nf < 4; ++nf) {
      f32x4 a = {0.f, 0.f, 0.f, 0.f};
#pragma unroll
      for (int ks = 0; ks < 2; ++ks) {
        bf16x8 fk = *(const bf16x8*)&sK[nf * 16 + lc][ks * 32 + g * 8];
        a = mfma16(fqw[ks], fk, a);
      }
      aa[nf] = a;
    }
#pragma unroll
    for (int r = 0; r < 4; ++r)
#pragma unroll
      for (int nf = 0; nf < 4; ++nf) p[r][nf] += aa[nf][r];

#pragma unroll
    for (int r = 0; r < 4; ++r) {
      float mt = fmaxf(fmaxf(p[r][0], p[r][1]), fmaxf(p[r][2], p[r][3]));
      mt = rmax16(mt);
      float mnew = fmaxf(mrun[r], mt);
      float corr = __expf(mrun[r] - mnew);
      mrun[r] = mnew;
      float se = 0.f;
#pragma unroll
      for (int nf = 0; nf < 4; ++nf) {
        float e = __expf(p[r][nf] - mnew);
        p[r][nf] = e;
        se += e;
      }
      se = rsum16(se);
      lsum[r] = lsum[r] * corr + se;
#pragma unroll
      for (int df = 0; df < 4; ++df) accO[df][r] *= corr;
#pragma unroll
      for (int nf = 0; nf < 4; ++nf)
        sP[w][g * 4 + r][nf * 16 + lc] = f2bf(p[r][nf]);
    }
#pragma unroll
    for (int ks = 0; ks < 2; ++ks) {
      bf16x8 fp = *(const bf16x8*)&sP[w][lc][ks * 32 + g * 8];
#pragma unroll
      for (int df = 0; df < 4; ++df) {
        bf16x8 fv = *(const bf16x8*)&sVT[df * 16 + lc][ks * 32 + g * 8];
        accO[df] = mfma16(fp, fv, accO[df]);
      }
    }
  }
#pragma unroll
  for (int r = 0; r < 4; ++r) {
    int i = i0 + w * 16 + g * 4 + r;
    size_t pb = ((size_t)(js * 32 + bn) * 1024 + i) * 64;
#pragma unroll
    for (int df = 0; df < 4; ++df) part[pb + df * 16 + lc] = accO[df][r];
    if (lc == 0) {
      size_t mb = (((size_t)js * 32 + bn) * 1024 + i) * 2;
      ml[mb] = mrun[r];
      ml[mb + 1] = lsum[r];
    }
  }
}

// ---------------- combine the two j-splits ----------------
__global__ __launch_bounds__(256) void combine_kernel(const float* __restrict__ part,
                                                      const float* __restrict__ ml,
                                                      unsigned short* __restrict__ av) {
  int gw = blockIdx.x * 4 + (threadIdx.x >> 6);
  int lane = threadIdx.x & 63;
  int bn = gw >> 10, i = gw & 1023;
  int b = bn >> 4, n = bn & 15;
  float m0 = ml[((size_t)bn * 1024 + i) * 2];
  float l0 = ml[((size_t)bn * 1024 + i) * 2 + 1];
  float m1 = ml[(((size_t)32 + bn) * 1024 + i) * 2];
  float l1 = ml[(((size_t)32 + bn) * 1024 + i) * 2 + 1];
  float mx = fmaxf(m0, m1);
  float w0 = __expf(m0 - mx), w1 = __expf(m1 - mx);
  float inv = 1.f / (l0 * w0 + l1 * w1);
  float o = part[((size_t)bn * 1024 + i) * 64 + lane] * w0 +
            part[(((size_t)32 + bn) * 1024 + i) * 64 + lane] * w1;
  av[((size_t)i * 2 + b) * 1024 + n * 64 + lane] = f2bf(o * inv);
}

// ---------------- residual + LayerNorm ----------------
__global__ __launch_bounds__(256) void ln_kernel(const float* __restrict__ gout,
                                                 const float* __restrict__ h,
                                                 const float* __restrict__ gamma,
                                                 const float* __restrict__ beta,
                                                 float* __restrict__ out) {
  __shared__ float red[8];
  const int row = blockIdx.x;
  const int tid = threadIdx.x;
  float x[4];
  float s = 0.f;
#pragma unroll
  for (int q = 0; q < 4; ++q) {
    int d = tid + q * 256;
    x[q] = gout[(size_t)row * 1024 + d] + h[(size_t)row * 1024 + d];
    s += x[q];
  }
#pragma unroll
  for (int m = 1; m < 64; m <<= 1) s += __shfl_xor(s, m);
  if ((tid & 63) == 0) red[tid >> 6] = s;
  __syncthreads();
  s = red[0] + red[1] + red[2] + red[3];
  float mu = s * (1.f / 1024.f);
  float v = 0.f;
#pragma unroll
  for (int q = 0; q < 4; ++q) {
    float dd = x[q] - mu;
    v += dd * dd;
  }
#pragma unroll
  for (int m = 1; m < 64; m <<= 1) v += __shfl_xor(v, m);
  if ((tid & 63) == 0) red[4 + (tid >> 6)] = v;
  __syncthreads();
  v = red[4] + red[5] + red[6] + red[7];
  float rstd = rsqrtf(v * (1.f / 1024.f) + 1e-12f);
#pragma unroll
  for (int q = 0; q < 4; ++q) {
    int d = tid + q * 256;
    out[(size_t)row * 1024 + d] = (x[q] - mu) * rstd * gamma[d] + beta[d];
  }
}

extern "C" void kernel_launch(void* const* d_in, const int* in_sizes, int n_in,
                              void* d_out, int out_size, void* d_ws, size_t ws_size,
                              hipStream_t stream) {
  const float* h = (const float*)d_in[0];
  const float* r = (const float*)d_in[1];
  const unsigned char* seg = (const unsigned char*)d_in[2];
  const float* mask = (const float*)d_in[3];
  const float* wq = (const float*)d_in[4];
  const float* wk = (const float*)d_in[5];
  const float* wv = (const float*)d_in[6];
  const float* wr = (const float*)d_in[7];
  const float* wo = (const float*)d_in[8];
  const float* rwb = (const float*)d_in[9];
  const float* rrb = (const float*)d_in[10];
  const float* rsb = (const float*)d_in[11];
  const float* seg_embed = (const float*)d_in[12];
  const float* gamma = (const float*)d_in[13];
  const float* beta = (const float*)d_in[14];
  float* out = (float*)d_out;

  char* ws = (char*)d_ws;
  size_t off = 0;
  auto alloc = [&](size_t bytes) {
    size_t cur = off;
    off = (off + bytes + 255) & ~(size_t)255;
    return cur;
  };
  unsigned short* hb = (unsigned short*)(ws + alloc(2048 * 1024 * 2));
  unsigned short* rb = (unsigned short*)(ws + alloc(4096 * 1024 * 2));
  unsigned short* wq_t = (unsigned short*)(ws + alloc(1024 * 1024 * 2));
  unsigned short* wk_t = (unsigned short*)(ws + alloc(1024 * 1024 * 2));
  unsigned short* wv_t = (unsigned short*)(ws + alloc(1024 * 1024 * 2));
  unsigned short* wr_t = (unsigned short*)(ws + alloc(1024 * 1024 * 2));
  unsigned short* wo_b = (unsigned short*)(ws + alloc(1024 * 1024 * 2));
  unsigned short* qwb = (unsigned short*)(ws + alloc(2048 * 1024 * 2));
  unsigned short* qrb = (unsigned short*)(ws + alloc(2048 * 1024 * 2));
  unsigned short* qsb = (unsigned short*)(ws + alloc(2048 * 1024 * 2));
  unsigned short* khb = (unsigned short*)(ws + alloc(2048 * 1024 * 2));
  unsigned short* vhb = (unsigned short*)(ws + alloc(2048 * 1024 * 2));
  unsigned short* krhb = (unsigned short*)(ws + alloc(4096 * 1024 * 2));
  unsigned short* vTb = (unsigned short*)(ws + alloc(2048 * 1024 * 2));
  float* ef0 = (float*)(ws + alloc(2048 * 16 * 4));
  float* ef1 = (float*)(ws + alloc(2048 * 16 * 4));
  unsigned int* segmask = (unsigned int*)(ws + alloc(2 * 1024 * 1024 * 4));
  unsigned short* avb = (unsigned short*)(ws + alloc(2048 * 1024 * 2));
  float* gout = (float*)(ws + alloc(2048 * 1024 * 4));
  float* part = (float*)(ws + alloc((size_t)2 * 32 * 1024 * 64 * 4));
  float* mlb = (float*)(ws + alloc((size_t)2 * 32 * 1024 * 2 * 4));
  (void)ws_size; (void)in_sizes; (void)n_in; (void)out_size;

  cast3_kernel<<<7168, 256, 0, stream>>>(h, r, wo, hb, rb, wo_b);
  transpose_cast4<<<dim3(32, 32, 4), 256, 0, stream>>>(wq, wk, wv, wr, wq_t, wk_t, wv_t, wr_t);
  segmask_kernel<<<4096, 256, 0, stream>>>(seg, mask, segmask);

  proj4_kernel<<<640, 256, 0, stream>>>(hb, rb, wq_t, wk_t, wv_t, wr_t, rwb, rrb, rsb,
                                        qwb, qrb, qsb, khb, vhb, krhb);

  transpose_v<<<dim3(16, 32), 256, 0, stream>>>(vhb, vTb);
  ef_kernel<<<8192, 256, 0, stream>>>(qsb, seg_embed, ef0, ef1);

  attn_kernel<<<dim3(32, 8, 2), 512, 0, stream>>>(qwb, qrb, khb, krhb, vTb,
                                                  ef0, ef1, segmask, part, mlb);
  combine_kernel<<<8192, 256, 0, stream>>>(part, mlb, avb);

  gemm64_out<<<dim3(8, 32), 256, 0, stream>>>(avb, wo_b, gout);
  ln_kernel<<<2048, 256, 0, stream>>>(gout, h, gamma, beta, out);
}

// Round 7
// 143.099 us; speedup vs baseline: 1.2740x; 1.0382x over previous
//
#include <hip/hip_runtime.h>

typedef __bf16 bf16x8 __attribute__((ext_vector_type(8)));
typedef float f32x4 __attribute__((ext_vector_type(4)));
typedef unsigned short us4 __attribute__((ext_vector_type(4)));

__device__ __forceinline__ unsigned short f2bf(float f) {
  unsigned int u = __builtin_bit_cast(unsigned int, f);
  u += 0x7fffu + ((u >> 16) & 1u);
  return (unsigned short)(u >> 16);
}
__device__ __forceinline__ float bf2f(unsigned short s) {
  unsigned int u = ((unsigned int)s) << 16;
  return __builtin_bit_cast(float, u);
}
__device__ __forceinline__ f32x4 mfma16(bf16x8 a, bf16x8 b, f32x4 c) {
  return __builtin_amdgcn_mfma_f32_16x16x32_bf16(a, b, c, 0, 0, 0);
}
__device__ __forceinline__ void gload16(const void* g, void* l) {
  __builtin_amdgcn_global_load_lds(
      (const __attribute__((address_space(1))) unsigned int*)g,
      (__attribute__((address_space(3))) unsigned int*)l, 16, 0, 0);
}
template <int CTRL>
__device__ __forceinline__ float dppf(float x) {
  return __builtin_bit_cast(
      float, __builtin_amdgcn_mov_dpp(__builtin_bit_cast(int, x), CTRL, 0xf, 0xf, true));
}
__device__ __forceinline__ float rmax16(float x) {
  x = fmaxf(x, dppf<0xB1>(x));
  x = fmaxf(x, dppf<0x4E>(x));
  x = fmaxf(x, dppf<0x124>(x));
  x = fmaxf(x, dppf<0x128>(x));
  return x;
}
__device__ __forceinline__ float rsum16(float x) {
  x += dppf<0xB1>(x);
  x += dppf<0x4E>(x);
  x += dppf<0x124>(x);
  x += dppf<0x128>(x);
  return x;
}

// ---------------- fused cast f32 -> bf16 for h, r, wo ----------------
__global__ __launch_bounds__(256) void cast3_kernel(
    const float* __restrict__ h, const float* __restrict__ r, const float* __restrict__ wo,
    unsigned short* __restrict__ hb, unsigned short* __restrict__ rb,
    unsigned short* __restrict__ wo_b) {
  int idx = blockIdx.x * 256 + threadIdx.x;  // float4 index
  const float* in;
  unsigned short* out;
  int o;
  if (idx < 524288) { in = h; out = hb; o = idx; }
  else if (idx < 1572864) { in = r; out = rb; o = idx - 524288; }
  else { in = wo; out = wo_b; o = idx - 1572864; }
  float4 v = ((const float4*)in)[o];
  us4 t;
  t[0] = f2bf(v.x); t[1] = f2bf(v.y); t[2] = f2bf(v.z); t[3] = f2bf(v.w);
  *(us4*)&out[o * 4] = t;
}

// ---------------- transpose+cast 4 weights [1024][1024] f32 -> [N][K] bf16 ----------------
__global__ __launch_bounds__(256) void transpose_cast4(
    const float* __restrict__ w0, const float* __restrict__ w1,
    const float* __restrict__ w2, const float* __restrict__ w3,
    unsigned short* __restrict__ o0, unsigned short* __restrict__ o1,
    unsigned short* __restrict__ o2, unsigned short* __restrict__ o3) {
  __shared__ float t[32][33];
  const int z = blockIdx.z;
  const float* in = z == 0 ? w0 : (z == 1 ? w1 : (z == 2 ? w2 : w3));
  unsigned short* out = z == 0 ? o0 : (z == 1 ? o1 : (z == 2 ? o2 : o3));
  int k0 = blockIdx.y * 32;
  int n0 = blockIdx.x * 32;
  int r = threadIdx.x >> 5;
  int c = threadIdx.x & 31;
#pragma unroll
  for (int s = 0; s < 4; ++s)
    t[r + s * 8][c] = in[(k0 + r + s * 8) * 1024 + n0 + c];
  __syncthreads();
#pragma unroll
  for (int s = 0; s < 4; ++s)
    out[(n0 + r + s * 8) * 1024 + k0 + c] = f2bf(t[c][r + s * 8]);
}

// ---------------- segmask: pack {bf16(-1e30*mask), bf16(seg)} per (b,i,j) ----------------
__global__ __launch_bounds__(256) void segmask_kernel(const unsigned char* __restrict__ seg,
                                                      const float* __restrict__ mask,
                                                      unsigned int* __restrict__ out) {
  int ij = blockIdx.x * 256 + threadIdx.x;
  unsigned short sv = *(const unsigned short*)&seg[ij * 2];
  float2 mv = *(const float2*)&mask[(size_t)ij * 2];
  unsigned int o0 = ((unsigned int)f2bf(mv.x * -1e30f) << 16) | ((sv & 0xffu) ? 0x3f80u : 0u);
  unsigned int o1 = ((unsigned int)f2bf(mv.y * -1e30f) << 16) | ((sv >> 8) ? 0x3f80u : 0u);
  out[ij] = o0;
  out[1048576 + ij] = o1;
}

// ---------------- all 4 projections: 128x128 tile, 8 waves, BK=64, 2-phase dbuf, swizzled ----------------
__global__ __launch_bounds__(512) void proj4_kernel(
    const unsigned short* __restrict__ hb, const unsigned short* __restrict__ rb,
    const unsigned short* __restrict__ wq_t, const unsigned short* __restrict__ wk_t,
    const unsigned short* __restrict__ wv_t, const unsigned short* __restrict__ wr_t,
    const float* __restrict__ rwb, const float* __restrict__ rrb, const float* __restrict__ rsb,
    unsigned short* __restrict__ qwb, unsigned short* __restrict__ qrb,
    unsigned short* __restrict__ qsb,
    unsigned short* __restrict__ khb, unsigned short* __restrict__ vhb,
    unsigned short* __restrict__ krhb) {
  __shared__ unsigned short sA[2][128 * 64];
  __shared__ unsigned short sB[2][128 * 64];
  const int bx = blockIdx.x;
  int sel, rblk;
  const unsigned short* A;
  if (bx < 384) { sel = bx >> 7; rblk = bx & 127; A = hb; }
  else { sel = 3; rblk = bx - 384; A = rb; }
  const unsigned short* Bt = sel == 0 ? wq_t : (sel == 1 ? wk_t : (sel == 2 ? wv_t : wr_t));
  const int n0 = (rblk & 7) * 128, m0 = (rblk >> 3) * 128;
  const int tid = threadIdx.x, lane = tid & 63, w = tid >> 6;  // 8 waves
  const int wm = w >> 1, wn = w & 1, g = lane >> 4, lc = lane & 15;
  // wave (wm,wn): rows wm*32 + mi*16 (mi<2), cols wn*64 + ni*16 (ni<4)

  f32x4 acc[2][4] = {};

  auto STAGE = [&](int buf, int kt) {
#pragma unroll
    for (int s = 0; s < 2; ++s) {
      int c = s * 512 + tid;
      int row = c >> 3;
      int ko = ((c & 7) ^ (row & 7)) * 8;  // pre-swizzled global slot
      int lbase = (s * 512 + w * 64) * 8;  // linear LDS dest (wave-uniform + lane*16B)
      gload16(&A[(size_t)(m0 + row) * 1024 + kt + ko], &sA[buf][lbase]);
      gload16(&Bt[(size_t)(n0 + row) * 1024 + kt + ko], &sB[buf][lbase]);
    }
  };

  STAGE(0, 0);
  __syncthreads();

  for (int kt = 0; kt < 1024; kt += 64) {
    const int cur = (kt >> 6) & 1;
    if (kt < 960) STAGE(cur ^ 1, kt + 64);
    bf16x8 af[2][2], bfr[4][2];
#pragma unroll
    for (int ks = 0; ks < 2; ++ks) {
#pragma unroll
      for (int mi = 0; mi < 2; ++mi) {
        int ra = wm * 32 + mi * 16 + lc;
        af[mi][ks] = *(const bf16x8*)&sA[cur][ra * 64 + (((ks * 4 + g) ^ (ra & 7)) * 8)];
      }
#pragma unroll
      for (int ni = 0; ni < 4; ++ni) {
        int rb_ = wn * 64 + ni * 16 + lc;
        bfr[ni][ks] = *(const bf16x8*)&sB[cur][rb_ * 64 + (((ks * 4 + g) ^ (rb_ & 7)) * 8)];
      }
    }
#pragma unroll
    for (int ks = 0; ks < 2; ++ks)
#pragma unroll
      for (int mi = 0; mi < 2; ++mi)
#pragma unroll
        for (int ni = 0; ni < 4; ++ni)
          acc[mi][ni] = mfma16(af[mi][ks], bfr[ni][ks], acc[mi][ni]);
    __syncthreads();
  }

#pragma unroll
  for (int ni = 0; ni < 4; ++ni) {
    int col = n0 + wn * 64 + ni * 16 + lc;
    float bw = 0.f, br = 0.f, bs = 0.f;
    if (sel == 0) { bw = rwb[col]; br = rrb[col]; bs = rsb[col]; }
#pragma unroll
    for (int mi = 0; mi < 2; ++mi) {
      int rowb = m0 + wm * 32 + mi * 16 + g * 4;
#pragma unroll
      for (int r = 0; r < 4; ++r) {
        float v = acc[mi][ni][r];
        size_t idx = (size_t)(rowb + r) * 1024 + col;
        if (sel == 0) {
          qwb[idx] = f2bf((v + bw) * 0.125f);
          qrb[idx] = f2bf((v + br) * 0.125f);
          qsb[idx] = f2bf((v + bs) * 0.125f);
        } else if (sel == 1) {
          khb[idx] = f2bf(v);
        } else if (sel == 2) {
          vhb[idx] = f2bf(v);
        } else {
          krhb[idx] = f2bf(v);
        }
      }
    }
  }
}

// ---------------- out-projection: 64x128 tile, 8 waves, BK=64, 2-phase dbuf, swizzled ----------------
__global__ __launch_bounds__(512) void gemm64_out(const unsigned short* __restrict__ A,
                                                  const unsigned short* __restrict__ Bt,
                                                  float* __restrict__ C) {
  __shared__ unsigned short sA[2][64 * 64];
  __shared__ unsigned short sB[2][128 * 64];
  const int tid = threadIdx.x, lane = tid & 63, w = tid >> 6;  // 8 waves
  const int wm = w >> 2, wn = w & 3, g = lane >> 4, lc = lane & 15;
  // wave (wm,wn): rows wm*32 + mi*16 (mi<2), cols wn*32 + ni*16 (ni<2)
  const int m0 = blockIdx.y * 64, n0 = blockIdx.x * 128;
  f32x4 acc[2][2] = {};

  auto STAGE = [&](int buf, int kt) {
    {
      int c = tid;  // 512 chunks of A (64 rows x 8)
      int row = c >> 3;
      int ko = ((c & 7) ^ (row & 7)) * 8;
      gload16(&A[(size_t)(m0 + row) * 1024 + kt + ko], &sA[buf][w * 64 * 8]);
    }
#pragma unroll
    for (int s = 0; s < 2; ++s) {
      int c = s * 512 + tid;
      int row = c >> 3;
      int ko = ((c & 7) ^ (row & 7)) * 8;
      gload16(&Bt[(size_t)(n0 + row) * 1024 + kt + ko], &sB[buf][(s * 512 + w * 64) * 8]);
    }
  };

  STAGE(0, 0);
  __syncthreads();

  for (int kt = 0; kt < 1024; kt += 64) {
    const int cur = (kt >> 6) & 1;
    if (kt < 960) STAGE(cur ^ 1, kt + 64);
    bf16x8 af[2][2], bfr[2][2];
#pragma unroll
    for (int ks = 0; ks < 2; ++ks) {
#pragma unroll
      for (int mi = 0; mi < 2; ++mi) {
        int ra = wm * 32 + mi * 16 + lc;
        af[mi][ks] = *(const bf16x8*)&sA[cur][ra * 64 + (((ks * 4 + g) ^ (ra & 7)) * 8)];
      }
#pragma unroll
      for (int ni = 0; ni < 2; ++ni) {
        int rb_ = wn * 32 + ni * 16 + lc;
        bfr[ni][ks] = *(const bf16x8*)&sB[cur][rb_ * 64 + (((ks * 4 + g) ^ (rb_ & 7)) * 8)];
      }
    }
#pragma unroll
    for (int ks = 0; ks < 2; ++ks)
#pragma unroll
      for (int mi = 0; mi < 2; ++mi)
#pragma unroll
        for (int ni = 0; ni < 2; ++ni)
          acc[mi][ni] = mfma16(af[mi][ks], bfr[ni][ks], acc[mi][ni]);
    __syncthreads();
  }
#pragma unroll
  for (int ni = 0; ni < 2; ++ni) {
    int col = n0 + wn * 32 + ni * 16 + lc;
#pragma unroll
    for (int mi = 0; mi < 2; ++mi) {
      int rowb = m0 + wm * 32 + mi * 16 + g * 4;
#pragma unroll
      for (int r = 0; r < 4; ++r)
        C[(size_t)(rowb + r) * 1024 + col] = acc[mi][ni][r];
    }
  }
}

// ---------------- V transpose ----------------
__global__ __launch_bounds__(256) void transpose_v(const unsigned short* __restrict__ vh,
                                                   unsigned short* __restrict__ vT) {
  __shared__ unsigned short t[64][65];
  const int bn = blockIdx.y, j0 = blockIdx.x * 64;
  const int b = bn >> 4, n = bn & 15;
  const int r = threadIdx.x >> 4;
  const int c4 = (threadIdx.x & 15) * 4;
#pragma unroll
  for (int s = 0; s < 4; ++s) {
    int j = r + s * 16;
    us4 v = *(const us4*)&vh[((size_t)(j0 + j) * 2 + b) * 1024 + n * 64 + c4];
    t[j][c4 + 0] = v[0]; t[j][c4 + 1] = v[1]; t[j][c4 + 2] = v[2]; t[j][c4 + 3] = v[3];
  }
  __syncthreads();
#pragma unroll
  for (int s = 0; s < 4; ++s) {
    int d = r + s * 16;
    us4 v;
    v[0] = t[c4 + 0][d]; v[1] = t[c4 + 1][d]; v[2] = t[c4 + 2][d]; v[3] = t[c4 + 3][d];
    *(us4*)&vT[((size_t)bn * 64 + d) * 1024 + j0 + c4] = v;
  }
}

// ---------------- ef0/ef1 per (i,b,n) ----------------
__global__ __launch_bounds__(256) void ef_kernel(const unsigned short* __restrict__ qs,
                                                 const float* __restrict__ seg_embed,
                                                 float* __restrict__ ef0, float* __restrict__ ef1) {
  int gw = blockIdx.x * 4 + (threadIdx.x >> 6);
  int lane = threadIdx.x & 63;
  int n = gw & 15, ib = gw >> 4;
  int i = ib >> 1, b = ib & 1;
  float qv = bf2f(qs[(size_t)ib * 1024 + n * 64 + lane]);
  float p0 = qv * seg_embed[n * 64 + lane];
  float p1 = qv * seg_embed[1024 + n * 64 + lane];
#pragma unroll
  for (int m = 1; m < 64; m <<= 1) {
    p0 += __shfl_xor(p0, m);
    p1 += __shfl_xor(p1, m);
  }
  if (lane == 0) {
    ef0[(b * 16 + n) * 1024 + i] = p0;
    ef1[(b * 16 + n) * 1024 + i] = p1;
  }
}

// ---------------- fused relative attention: BI=128, 8 waves, j-split x2 ----------------
__global__ __launch_bounds__(512, 4) void attn_kernel(
    const unsigned short* __restrict__ qw, const unsigned short* __restrict__ qr,
    const unsigned short* __restrict__ kh, const unsigned short* __restrict__ krh,
    const unsigned short* __restrict__ vT,
    const float* __restrict__ ef0, const float* __restrict__ ef1,
    const unsigned int* __restrict__ segmask,
    float* __restrict__ part, float* __restrict__ ml) {
  __shared__ unsigned short sK[64][72];
  __shared__ unsigned short sVT[64][72];
  __shared__ unsigned short sKR[256][72];  // circular band, slot = jr & 255
  __shared__ unsigned short sP[8][16][80];

  const int tid = threadIdx.x, lane = tid & 63, w = tid >> 6;  // w: 0..7
  const int g = lane >> 4, lc = lane & 15;
  const int bn = blockIdx.x, b = bn >> 4, n = bn & 15;
  const int i0 = blockIdx.y * 128;
  const int js = blockIdx.z;
  const int S0 = 1024 + js * 512 - i0 - 127;

  bf16x8 fqw[2], fqr[2];
  const int qrow = i0 + w * 16 + lc;
#pragma unroll
  for (int ks = 0; ks < 2; ++ks) {
    size_t off = ((size_t)qrow * 2 + b) * 1024 + n * 64 + ks * 32 + g * 8;
    fqw[ks] = *(const bf16x8*)&qw[off];
    fqr[ks] = *(const bf16x8*)&qr[off];
  }
  float ef0v[4], dv[4];
  unsigned int smoff[4];
#pragma unroll
  for (int r = 0; r < 4; ++r) {
    int i = i0 + w * 16 + g * 4 + r;
    float e0 = ef0[bn * 1024 + i];
    ef0v[r] = e0;
    dv[r] = ef1[bn * 1024 + i] - e0;
    smoff[r] = ((unsigned)b << 20) | ((unsigned)i << 10) | (unsigned)lc;
  }
  float mrun[4], lsum[4];
  f32x4 accO[4] = {};
#pragma unroll
  for (int r = 0; r < 4; ++r) { mrun[r] = -3e38f; lsum[r] = 0.f; }

  const int srow = tid >> 3;
  const int sko = (tid & 7) * 8;

#pragma unroll
  for (int pp = 0; pp < 3; ++pp) {
    int jr = S0 + pp * 64 + srow;
    *(uint4*)&sKR[jr & 255][sko] =
        *(const uint4*)&krh[((size_t)jr * 2 + b) * 1024 + n * 64 + sko];
  }
  int j0 = js * 512;
  uint4 rK = *(const uint4*)&kh[((size_t)(j0 + srow) * 2 + b) * 1024 + n * 64 + sko];
  uint4 rV = *(const uint4*)&vT[((size_t)bn * 64 + srow) * 1024 + j0 + sko];
  uint4 rR = *(const uint4*)&krh[((size_t)(S0 + 192 + srow) * 2 + b) * 1024 + n * 64 + sko];

  for (int t = 0; t < 8; ++t) {
    j0 = (js * 8 + t) * 64;
    __syncthreads();
    *(uint4*)&sK[srow][sko] = rK;
    *(uint4*)&sVT[srow][sko] = rV;
    if (t < 7) {
      *(uint4*)&sKR[(S0 + 192 + t * 64 + srow) & 255][sko] = rR;
      int j0n = j0 + 64;
      rK = *(const uint4*)&kh[((size_t)(j0n + srow) * 2 + b) * 1024 + n * 64 + sko];
      rV = *(const uint4*)&vT[((size_t)bn * 64 + srow) * 1024 + j0n + sko];
      if (t < 6) {
        int jr = S0 + 256 + t * 64 + srow;
        if (jr > 2047) jr = 2047;
        rR = *(const uint4*)&krh[((size_t)jr * 2 + b) * 1024 + n * 64 + sko];
      }
    }
    unsigned int msv[4][4];
#pragma unroll
    for (int r = 0; r < 4; ++r)
#pragma unroll
      for (int nf = 0; nf < 4; ++nf)
        msv[r][nf] = segmask[smoff[r] + j0 + nf * 16];
    __syncthreads();

    const int base = S0 + t * 64 + (7 - w) * 16;
    f32x4 bdk[5];
#pragma unroll
    for (int k = 0; k < 5; ++k) {
      f32x4 a = {0.f, 0.f, 0.f, 0.f};
#pragma unroll
      for (int ks = 0; ks < 2; ++ks) {
        bf16x8 fk = *(const bf16x8*)&sKR[(base + k * 16 + lc) & 255][ks * 32 + g * 8];
        a = mfma16(fqr[ks], fk, a);
      }
      bdk[k] = a;
    }
    float p[4][4];
#pragma unroll
    for (int r = 0; r < 4; ++r) {
      const int a_ = g * 4 + r;
      const int srcl = (lane & 48) | ((lc + 15 - a_) & 15);
      float s0 = __shfl(bdk[0][r], srcl);
      float s1 = __shfl(bdk[1][r], srcl);
      float s2 = __shfl(bdk[2][r], srcl);
      float s3 = __shfl(bdk[3][r], srcl);
      float s4 = __shfl(bdk[4][r], srcl);
      const bool lo = lc <= a_;
#pragma unroll
      for (int nf = 0; nf < 4; ++nf) {
        unsigned int u = msv[r][nf];
        float sgv = bf2f((unsigned short)(u & 0xffffu));
        float mkv = bf2f((unsigned short)(u >> 16));
        float bdv = lo ? (nf == 0 ? s0 : nf == 1 ? s1 : nf == 2 ? s2 : s3)
                       : (nf == 0 ? s1 : nf == 1 ? s2 : nf == 2 ? s3 : s4);
        p[r][nf] = ef0v[r] + sgv * dv[r] + mkv + bdv;
      }
    }
    f32x4 aa[4];
#pragma unroll
    for (int nf = 0; nf < 4; ++nf) {
      f32x4 a = {0.f, 0.f, 0.f, 0.f};
#pragma unroll
      for (int ks = 0; ks < 2; ++ks) {
        bf16x8 fk = *(const bf16x8*)&sK[nf * 16 + lc][ks * 32 + g * 8];
        a = mfma16(fqw[ks], fk, a);
      }
      aa[nf] = a;
    }
#pragma unroll
    for (int r = 0; r < 4; ++r)
#pragma unroll
      for (int nf = 0; nf < 4; ++nf) p[r][nf] += aa[nf][r];

#pragma unroll
    for (int r = 0; r < 4; ++r) {
      float mt = fmaxf(fmaxf(p[r][0], p[r][1]), fmaxf(p[r][2], p[r][3]));
      mt = rmax16(mt);
      float mnew = fmaxf(mrun[r], mt);
      float corr = __expf(mrun[r] - mnew);
      mrun[r] = mnew;
      float se = 0.f;
#pragma unroll
      for (int nf = 0; nf < 4; ++nf) {
        float e = __expf(p[r][nf] - mnew);
        p[r][nf] = e;
        se += e;
      }
      se = rsum16(se);
      lsum[r] = lsum[r] * corr + se;
#pragma unroll
      for (int df = 0; df < 4; ++df) accO[df][r] *= corr;
#pragma unroll
      for (int nf = 0; nf < 4; ++nf)
        sP[w][g * 4 + r][nf * 16 + lc] = f2bf(p[r][nf]);
    }
#pragma unroll
    for (int ks = 0; ks < 2; ++ks) {
      bf16x8 fp = *(const bf16x8*)&sP[w][lc][ks * 32 + g * 8];
#pragma unroll
      for (int df = 0; df < 4; ++df) {
        bf16x8 fv = *(const bf16x8*)&sVT[df * 16 + lc][ks * 32 + g * 8];
        accO[df] = mfma16(fp, fv, accO[df]);
      }
    }
  }
#pragma unroll
  for (int r = 0; r < 4; ++r) {
    int i = i0 + w * 16 + g * 4 + r;
    size_t pb = ((size_t)(js * 32 + bn) * 1024 + i) * 64;
#pragma unroll
    for (int df = 0; df < 4; ++df) part[pb + df * 16 + lc] = accO[df][r];
    if (lc == 0) {
      size_t mb = (((size_t)js * 32 + bn) * 1024 + i) * 2;
      ml[mb] = mrun[r];
      ml[mb + 1] = lsum[r];
    }
  }
}

// ---------------- combine the two j-splits ----------------
__global__ __launch_bounds__(256) void combine_kernel(const float* __restrict__ part,
                                                      const float* __restrict__ ml,
                                                      unsigned short* __restrict__ av) {
  int gw = blockIdx.x * 4 + (threadIdx.x >> 6);
  int lane = threadIdx.x & 63;
  int bn = gw >> 10, i = gw & 1023;
  int b = bn >> 4, n = bn & 15;
  float m0 = ml[((size_t)bn * 1024 + i) * 2];
  float l0 = ml[((size_t)bn * 1024 + i) * 2 + 1];
  float m1 = ml[(((size_t)32 + bn) * 1024 + i) * 2];
  float l1 = ml[(((size_t)32 + bn) * 1024 + i) * 2 + 1];
  float mx = fmaxf(m0, m1);
  float w0 = __expf(m0 - mx), w1 = __expf(m1 - mx);
  float inv = 1.f / (l0 * w0 + l1 * w1);
  float o = part[((size_t)bn * 1024 + i) * 64 + lane] * w0 +
            part[(((size_t)32 + bn) * 1024 + i) * 64 + lane] * w1;
  av[((size_t)i * 2 + b) * 1024 + n * 64 + lane] = f2bf(o * inv);
}

// ---------------- residual + LayerNorm ----------------
__global__ __launch_bounds__(256) void ln_kernel(const float* __restrict__ gout,
                                                 const float* __restrict__ h,
                                                 const float* __restrict__ gamma,
                                                 const float* __restrict__ beta,
                                                 float* __restrict__ out) {
  __shared__ float red[8];
  const int row = blockIdx.x;
  const int tid = threadIdx.x;
  float x[4];
  float s = 0.f;
#pragma unroll
  for (int q = 0; q < 4; ++q) {
    int d = tid + q * 256;
    x[q] = gout[(size_t)row * 1024 + d] + h[(size_t)row * 1024 + d];
    s += x[q];
  }
#pragma unroll
  for (int m = 1; m < 64; m <<= 1) s += __shfl_xor(s, m);
  if ((tid & 63) == 0) red[tid >> 6] = s;
  __syncthreads();
  s = red[0] + red[1] + red[2] + red[3];
  float mu = s * (1.f / 1024.f);
  float v = 0.f;
#pragma unroll
  for (int q = 0; q < 4; ++q) {
    float dd = x[q] - mu;
    v += dd * dd;
  }
#pragma unroll
  for (int m = 1; m < 64; m <<= 1) v += __shfl_xor(v, m);
  if ((tid & 63) == 0) red[4 + (tid >> 6)] = v;
  __syncthreads();
  v = red[4] + red[5] + red[6] + red[7];
  float rstd = rsqrtf(v * (1.f / 1024.f) + 1e-12f);
#pragma unroll
  for (int q = 0; q < 4; ++q) {
    int d = tid + q * 256;
    out[(size_t)row * 1024 + d] = (x[q] - mu) * rstd * gamma[d] + beta[d];
  }
}

extern "C" void kernel_launch(void* const* d_in, const int* in_sizes, int n_in,
                              void* d_out, int out_size, void* d_ws, size_t ws_size,
                              hipStream_t stream) {
  const float* h = (const float*)d_in[0];
  const float* r = (const float*)d_in[1];
  const unsigned char* seg = (const unsigned char*)d_in[2];
  const float* mask = (const float*)d_in[3];
  const float* wq = (const float*)d_in[4];
  const float* wk = (const float*)d_in[5];
  const float* wv = (const float*)d_in[6];
  const float* wr = (const float*)d_in[7];
  const float* wo = (const float*)d_in[8];
  const float* rwb = (const float*)d_in[9];
  const float* rrb = (const float*)d_in[10];
  const float* rsb = (const float*)d_in[11];
  const float* seg_embed = (const float*)d_in[12];
  const float* gamma = (const float*)d_in[13];
  const float* beta = (const float*)d_in[14];
  float* out = (float*)d_out;

  char* ws = (char*)d_ws;
  size_t off = 0;
  auto alloc = [&](size_t bytes) {
    size_t cur = off;
    off = (off + bytes + 255) & ~(size_t)255;
    return cur;
  };
  unsigned short* hb = (unsigned short*)(ws + alloc(2048 * 1024 * 2));
  unsigned short* rb = (unsigned short*)(ws + alloc(4096 * 1024 * 2));
  unsigned short* wq_t = (unsigned short*)(ws + alloc(1024 * 1024 * 2));
  unsigned short* wk_t = (unsigned short*)(ws + alloc(1024 * 1024 * 2));
  unsigned short* wv_t = (unsigned short*)(ws + alloc(1024 * 1024 * 2));
  unsigned short* wr_t = (unsigned short*)(ws + alloc(1024 * 1024 * 2));
  unsigned short* wo_b = (unsigned short*)(ws + alloc(1024 * 1024 * 2));
  unsigned short* qwb = (unsigned short*)(ws + alloc(2048 * 1024 * 2));
  unsigned short* qrb = (unsigned short*)(ws + alloc(2048 * 1024 * 2));
  unsigned short* qsb = (unsigned short*)(ws + alloc(2048 * 1024 * 2));
  unsigned short* khb = (unsigned short*)(ws + alloc(2048 * 1024 * 2));
  unsigned short* vhb = (unsigned short*)(ws + alloc(2048 * 1024 * 2));
  unsigned short* krhb = (unsigned short*)(ws + alloc(4096 * 1024 * 2));
  unsigned short* vTb = (unsigned short*)(ws + alloc(2048 * 1024 * 2));
  float* ef0 = (float*)(ws + alloc(2048 * 16 * 4));
  float* ef1 = (float*)(ws + alloc(2048 * 16 * 4));
  unsigned int* segmask = (unsigned int*)(ws + alloc(2 * 1024 * 1024 * 4));
  unsigned short* avb = (unsigned short*)(ws + alloc(2048 * 1024 * 2));
  float* gout = (float*)(ws + alloc(2048 * 1024 * 4));
  float* part = (float*)(ws + alloc((size_t)2 * 32 * 1024 * 64 * 4));
  float* mlb = (float*)(ws + alloc((size_t)2 * 32 * 1024 * 2 * 4));
  (void)ws_size; (void)in_sizes; (void)n_in; (void)out_size;

  cast3_kernel<<<7168, 256, 0, stream>>>(h, r, wo, hb, rb, wo_b);
  transpose_cast4<<<dim3(32, 32, 4), 256, 0, stream>>>(wq, wk, wv, wr, wq_t, wk_t, wv_t, wr_t);
  segmask_kernel<<<4096, 256, 0, stream>>>(seg, mask, segmask);

  proj4_kernel<<<640, 512, 0, stream>>>(hb, rb, wq_t, wk_t, wv_t, wr_t, rwb, rrb, rsb,
                                        qwb, qrb, qsb, khb, vhb, krhb);

  transpose_v<<<dim3(16, 32), 256, 0, stream>>>(vhb, vTb);
  ef_kernel<<<8192, 256, 0, stream>>>(qsb, seg_embed, ef0, ef1);

  attn_kernel<<<dim3(32, 8, 2), 512, 0, stream>>>(qwb, qrb, khb, krhb, vTb,
                                                  ef0, ef1, segmask, part, mlb);
  combine_kernel<<<8192, 256, 0, stream>>>(part, mlb, avb);

  gemm64_out<<<dim3(8, 32), 512, 0, stream>>>(avb, wo_b, gout);
  ln_kernel<<<2048, 256, 0, stream>>>(gout, h, gamma, beta, out);
}

// Round 8
// 140.016 us; speedup vs baseline: 1.3020x; 1.0220x over previous
//
#include <hip/hip_runtime.h>

typedef __bf16 bf16x8 __attribute__((ext_vector_type(8)));
typedef float f32x4 __attribute__((ext_vector_type(4)));
typedef unsigned short us4 __attribute__((ext_vector_type(4)));

__device__ __forceinline__ unsigned short f2bf(float f) {
  unsigned int u = __builtin_bit_cast(unsigned int, f);
  u += 0x7fffu + ((u >> 16) & 1u);
  return (unsigned short)(u >> 16);
}
__device__ __forceinline__ float bf2f(unsigned short s) {
  unsigned int u = ((unsigned int)s) << 16;
  return __builtin_bit_cast(float, u);
}
__device__ __forceinline__ f32x4 mfma16(bf16x8 a, bf16x8 b, f32x4 c) {
  return __builtin_amdgcn_mfma_f32_16x16x32_bf16(a, b, c, 0, 0, 0);
}
__device__ __forceinline__ void gload16(const void* g, void* l) {
  __builtin_amdgcn_global_load_lds(
      (const __attribute__((address_space(1))) unsigned int*)g,
      (__attribute__((address_space(3))) unsigned int*)l, 16, 0, 0);
}
template <int CTRL>
__device__ __forceinline__ float dppf(float x) {
  return __builtin_bit_cast(
      float, __builtin_amdgcn_mov_dpp(__builtin_bit_cast(int, x), CTRL, 0xf, 0xf, true));
}
__device__ __forceinline__ float rmax16(float x) {
  x = fmaxf(x, dppf<0xB1>(x));
  x = fmaxf(x, dppf<0x4E>(x));
  x = fmaxf(x, dppf<0x124>(x));
  x = fmaxf(x, dppf<0x128>(x));
  return x;
}
__device__ __forceinline__ float rsum16(float x) {
  x += dppf<0xB1>(x);
  x += dppf<0x4E>(x);
  x += dppf<0x124>(x);
  x += dppf<0x128>(x);
  return x;
}

// ---------------- fused cast f32 -> bf16 for h, r, wo ----------------
__global__ __launch_bounds__(256) void cast3_kernel(
    const float* __restrict__ h, const float* __restrict__ r, const float* __restrict__ wo,
    unsigned short* __restrict__ hb, unsigned short* __restrict__ rb,
    unsigned short* __restrict__ wo_b) {
  int idx = blockIdx.x * 256 + threadIdx.x;  // float4 index
  const float* in;
  unsigned short* out;
  int o;
  if (idx < 524288) { in = h; out = hb; o = idx; }
  else if (idx < 1572864) { in = r; out = rb; o = idx - 524288; }
  else { in = wo; out = wo_b; o = idx - 1572864; }
  float4 v = ((const float4*)in)[o];
  us4 t;
  t[0] = f2bf(v.x); t[1] = f2bf(v.y); t[2] = f2bf(v.z); t[3] = f2bf(v.w);
  *(us4*)&out[o * 4] = t;
}

// ---------------- transpose+cast 4 weights [1024][1024] f32 -> [N][K] bf16 ----------------
__global__ __launch_bounds__(256) void transpose_cast4(
    const float* __restrict__ w0, const float* __restrict__ w1,
    const float* __restrict__ w2, const float* __restrict__ w3,
    unsigned short* __restrict__ o0, unsigned short* __restrict__ o1,
    unsigned short* __restrict__ o2, unsigned short* __restrict__ o3) {
  __shared__ float t[32][33];
  const int z = blockIdx.z;
  const float* in = z == 0 ? w0 : (z == 1 ? w1 : (z == 2 ? w2 : w3));
  unsigned short* out = z == 0 ? o0 : (z == 1 ? o1 : (z == 2 ? o2 : o3));
  int k0 = blockIdx.y * 32;
  int n0 = blockIdx.x * 32;
  int r = threadIdx.x >> 5;
  int c = threadIdx.x & 31;
#pragma unroll
  for (int s = 0; s < 4; ++s)
    t[r + s * 8][c] = in[(k0 + r + s * 8) * 1024 + n0 + c];
  __syncthreads();
#pragma unroll
  for (int s = 0; s < 4; ++s)
    out[(n0 + r + s * 8) * 1024 + k0 + c] = f2bf(t[c][r + s * 8]);
}

// ---------------- segmask: pack {bf16(-1e30*mask), bf16(seg)} per (b,i,j) ----------------
__global__ __launch_bounds__(256) void segmask_kernel(const unsigned char* __restrict__ seg,
                                                      const float* __restrict__ mask,
                                                      unsigned int* __restrict__ out) {
  int ij = blockIdx.x * 256 + threadIdx.x;
  unsigned short sv = *(const unsigned short*)&seg[ij * 2];
  float2 mv = *(const float2*)&mask[(size_t)ij * 2];
  unsigned int o0 = ((unsigned int)f2bf(mv.x * -1e30f) << 16) | ((sv & 0xffu) ? 0x3f80u : 0u);
  unsigned int o1 = ((unsigned int)f2bf(mv.y * -1e30f) << 16) | ((sv >> 8) ? 0x3f80u : 0u);
  out[ij] = o0;
  out[1048576 + ij] = o1;
}

// ---------------- all 4 projections: 128x128 tile, 8 waves, K=32 sub-tiles,
// 4-slot counted-vmcnt pipeline (T3+T4), 2-way-free LDS swizzle ----------------
__global__ __launch_bounds__(512) void proj4_kernel(
    const unsigned short* __restrict__ hb, const unsigned short* __restrict__ rb,
    const unsigned short* __restrict__ wq_t, const unsigned short* __restrict__ wk_t,
    const unsigned short* __restrict__ wv_t, const unsigned short* __restrict__ wr_t,
    const float* __restrict__ rwb, const float* __restrict__ rrb, const float* __restrict__ rsb,
    unsigned short* __restrict__ qwb, unsigned short* __restrict__ qrb,
    unsigned short* __restrict__ qsb,
    unsigned short* __restrict__ khb, unsigned short* __restrict__ vhb,
    unsigned short* __restrict__ krhb) {
  __shared__ unsigned short sA[4][128 * 32];
  __shared__ unsigned short sB[4][128 * 32];
  const int bx = blockIdx.x;
  int sel, rblk;
  const unsigned short* A;
  if (bx < 384) { sel = bx >> 7; rblk = bx & 127; A = hb; }
  else { sel = 3; rblk = bx - 384; A = rb; }
  const unsigned short* Bt = sel == 0 ? wq_t : (sel == 1 ? wk_t : (sel == 2 ? wv_t : wr_t));
  const int n0 = (rblk & 7) * 128, m0 = (rblk >> 3) * 128;
  const int tid = threadIdx.x, lane = tid & 63, w = tid >> 6;  // 8 waves
  const int wm = w >> 1, wn = w & 1, g = lane >> 4, lc = lane & 15;

  f32x4 acc[2][4] = {};

  // staging role: 1 chunk (16B) of A and of B per thread per sub-tile.
  // physical slot = tid&3; holds global k-chunk (slot ^ (row>>1)&3) so the
  // swizzled READ (g ^ (row>>1)&3) is the free-2-way pattern (both-sides rule).
  const int srow = tid >> 2;
  const int sslot = tid & 3;
  const int sko = (sslot ^ ((srow >> 1) & 3)) * 8;
  const unsigned short* aptr = &A[(size_t)(m0 + srow) * 1024 + sko];
  const unsigned short* bptr = &Bt[(size_t)(n0 + srow) * 1024 + sko];
  const int ldst = w * 64 * 8;  // wave-uniform LDS base (shorts); +lane*16B implicit

  auto STAGE = [&](int slot, int kt) {
    gload16(aptr + kt, &sA[slot][ldst]);
    gload16(bptr + kt, &sB[slot][ldst]);
  };
  auto COMPUTE = [&](int slot) {
    bf16x8 af[2], bfr[4];
#pragma unroll
    for (int mi = 0; mi < 2; ++mi) {
      int ra = wm * 32 + mi * 16 + lc;
      af[mi] = *(const bf16x8*)&sA[slot][ra * 32 + ((g ^ ((ra >> 1) & 3)) * 8)];
    }
#pragma unroll
    for (int ni = 0; ni < 4; ++ni) {
      int rb_ = wn * 64 + ni * 16 + lc;
      bfr[ni] = *(const bf16x8*)&sB[slot][rb_ * 32 + ((g ^ ((rb_ >> 1) & 3)) * 8)];
    }
    __builtin_amdgcn_s_setprio(1);
#pragma unroll
    for (int mi = 0; mi < 2; ++mi)
#pragma unroll
      for (int ni = 0; ni < 4; ++ni)
        acc[mi][ni] = mfma16(af[mi], bfr[ni], acc[mi][ni]);
    __builtin_amdgcn_s_setprio(0);
  };

  // prologue: 3 sub-tiles in flight (6 loads/thread)
  STAGE(0, 0);
  STAGE(1, 32);
  STAGE(2, 64);
  // steady state: wait vmcnt(4) retires the oldest stage (<=3 stages * 2 loads in flight)
  for (int s = 0; s < 30; ++s) {
    asm volatile("s_waitcnt vmcnt(4)" ::: "memory");
    __builtin_amdgcn_s_barrier();
    asm volatile("" ::: "memory");
    if (s < 29) STAGE((s + 3) & 3, (s + 3) * 32);
    COMPUTE(s & 3);
  }
  asm volatile("s_waitcnt vmcnt(2)" ::: "memory");
  __builtin_amdgcn_s_barrier();
  asm volatile("" ::: "memory");
  COMPUTE(2);  // s = 30
  asm volatile("s_waitcnt vmcnt(0)" ::: "memory");
  __builtin_amdgcn_s_barrier();
  asm volatile("" ::: "memory");
  COMPUTE(3);  // s = 31

#pragma unroll
  for (int ni = 0; ni < 4; ++ni) {
    int col = n0 + wn * 64 + ni * 16 + lc;
    float bw = 0.f, br = 0.f, bs = 0.f;
    if (sel == 0) { bw = rwb[col]; br = rrb[col]; bs = rsb[col]; }
#pragma unroll
    for (int mi = 0; mi < 2; ++mi) {
      int rowb = m0 + wm * 32 + mi * 16 + g * 4;
#pragma unroll
      for (int r = 0; r < 4; ++r) {
        float v = acc[mi][ni][r];
        size_t idx = (size_t)(rowb + r) * 1024 + col;
        if (sel == 0) {
          qwb[idx] = f2bf((v + bw) * 0.125f);
          qrb[idx] = f2bf((v + br) * 0.125f);
          qsb[idx] = f2bf((v + bs) * 0.125f);
        } else if (sel == 1) {
          khb[idx] = f2bf(v);
        } else if (sel == 2) {
          vhb[idx] = f2bf(v);
        } else {
          krhb[idx] = f2bf(v);
        }
      }
    }
  }
}

// ---------------- out-projection: 64x128 tile, 8 waves, BK=64, 2-phase dbuf, swizzled ----------------
__global__ __launch_bounds__(512) void gemm64_out(const unsigned short* __restrict__ A,
                                                  const unsigned short* __restrict__ Bt,
                                                  float* __restrict__ C) {
  __shared__ unsigned short sA[2][64 * 64];
  __shared__ unsigned short sB[2][128 * 64];
  const int tid = threadIdx.x, lane = tid & 63, w = tid >> 6;  // 8 waves
  const int wm = w >> 2, wn = w & 3, g = lane >> 4, lc = lane & 15;
  const int m0 = blockIdx.y * 64, n0 = blockIdx.x * 128;
  f32x4 acc[2][2] = {};

  auto STAGE = [&](int buf, int kt) {
    {
      int c = tid;  // 512 chunks of A (64 rows x 8)
      int row = c >> 3;
      int ko = ((c & 7) ^ (row & 7)) * 8;
      gload16(&A[(size_t)(m0 + row) * 1024 + kt + ko], &sA[buf][w * 64 * 8]);
    }
#pragma unroll
    for (int s = 0; s < 2; ++s) {
      int c = s * 512 + tid;
      int row = c >> 3;
      int ko = ((c & 7) ^ (row & 7)) * 8;
      gload16(&Bt[(size_t)(n0 + row) * 1024 + kt + ko], &sB[buf][(s * 512 + w * 64) * 8]);
    }
  };

  STAGE(0, 0);
  __syncthreads();

  for (int kt = 0; kt < 1024; kt += 64) {
    const int cur = (kt >> 6) & 1;
    if (kt < 960) STAGE(cur ^ 1, kt + 64);
    bf16x8 af[2][2], bfr[2][2];
#pragma unroll
    for (int ks = 0; ks < 2; ++ks) {
#pragma unroll
      for (int mi = 0; mi < 2; ++mi) {
        int ra = wm * 32 + mi * 16 + lc;
        af[mi][ks] = *(const bf16x8*)&sA[cur][ra * 64 + (((ks * 4 + g) ^ (ra & 7)) * 8)];
      }
#pragma unroll
      for (int ni = 0; ni < 2; ++ni) {
        int rb_ = wn * 32 + ni * 16 + lc;
        bfr[ni][ks] = *(const bf16x8*)&sB[cur][rb_ * 64 + (((ks * 4 + g) ^ (rb_ & 7)) * 8)];
      }
    }
#pragma unroll
    for (int ks = 0; ks < 2; ++ks)
#pragma unroll
      for (int mi = 0; mi < 2; ++mi)
#pragma unroll
        for (int ni = 0; ni < 2; ++ni)
          acc[mi][ni] = mfma16(af[mi][ks], bfr[ni][ks], acc[mi][ni]);
    __syncthreads();
  }
#pragma unroll
  for (int ni = 0; ni < 2; ++ni) {
    int col = n0 + wn * 32 + ni * 16 + lc;
#pragma unroll
    for (int mi = 0; mi < 2; ++mi) {
      int rowb = m0 + wm * 32 + mi * 16 + g * 4;
#pragma unroll
      for (int r = 0; r < 4; ++r)
        C[(size_t)(rowb + r) * 1024 + col] = acc[mi][ni][r];
    }
  }
}

// ---------------- V transpose ----------------
__global__ __launch_bounds__(256) void transpose_v(const unsigned short* __restrict__ vh,
                                                   unsigned short* __restrict__ vT) {
  __shared__ unsigned short t[64][65];
  const int bn = blockIdx.y, j0 = blockIdx.x * 64;
  const int b = bn >> 4, n = bn & 15;
  const int r = threadIdx.x >> 4;
  const int c4 = (threadIdx.x & 15) * 4;
#pragma unroll
  for (int s = 0; s < 4; ++s) {
    int j = r + s * 16;
    us4 v = *(const us4*)&vh[((size_t)(j0 + j) * 2 + b) * 1024 + n * 64 + c4];
    t[j][c4 + 0] = v[0]; t[j][c4 + 1] = v[1]; t[j][c4 + 2] = v[2]; t[j][c4 + 3] = v[3];
  }
  __syncthreads();
#pragma unroll
  for (int s = 0; s < 4; ++s) {
    int d = r + s * 16;
    us4 v;
    v[0] = t[c4 + 0][d]; v[1] = t[c4 + 1][d]; v[2] = t[c4 + 2][d]; v[3] = t[c4 + 3][d];
    *(us4*)&vT[((size_t)bn * 64 + d) * 1024 + j0 + c4] = v;
  }
}

// ---------------- ef0/ef1 per (i,b,n) ----------------
__global__ __launch_bounds__(256) void ef_kernel(const unsigned short* __restrict__ qs,
                                                 const float* __restrict__ seg_embed,
                                                 float* __restrict__ ef0, float* __restrict__ ef1) {
  int gw = blockIdx.x * 4 + (threadIdx.x >> 6);
  int lane = threadIdx.x & 63;
  int n = gw & 15, ib = gw >> 4;
  int i = ib >> 1, b = ib & 1;
  float qv = bf2f(qs[(size_t)ib * 1024 + n * 64 + lane]);
  float p0 = qv * seg_embed[n * 64 + lane];
  float p1 = qv * seg_embed[1024 + n * 64 + lane];
#pragma unroll
  for (int m = 1; m < 64; m <<= 1) {
    p0 += __shfl_xor(p0, m);
    p1 += __shfl_xor(p1, m);
  }
  if (lane == 0) {
    ef0[(b * 16 + n) * 1024 + i] = p0;
    ef1[(b * 16 + n) * 1024 + i] = p1;
  }
}

// ---------------- fused relative attention: BI=128, 8 waves, j-split x2 ----------------
__global__ __launch_bounds__(512, 4) void attn_kernel(
    const unsigned short* __restrict__ qw, const unsigned short* __restrict__ qr,
    const unsigned short* __restrict__ kh, const unsigned short* __restrict__ krh,
    const unsigned short* __restrict__ vT,
    const float* __restrict__ ef0, const float* __restrict__ ef1,
    const unsigned int* __restrict__ segmask,
    float* __restrict__ part, float* __restrict__ ml) {
  __shared__ unsigned short sK[64][72];
  __shared__ unsigned short sVT[64][72];
  __shared__ unsigned short sKR[256][72];  // circular band, slot = jr & 255
  __shared__ unsigned short sP[8][16][80];

  const int tid = threadIdx.x, lane = tid & 63, w = tid >> 6;  // w: 0..7
  const int g = lane >> 4, lc = lane & 15;
  const int bn = blockIdx.x, b = bn >> 4, n = bn & 15;
  const int i0 = blockIdx.y * 128;
  const int js = blockIdx.z;
  const int S0 = 1024 + js * 512 - i0 - 127;

  bf16x8 fqw[2], fqr[2];
  const int qrow = i0 + w * 16 + lc;
#pragma unroll
  for (int ks = 0; ks < 2; ++ks) {
    size_t off = ((size_t)qrow * 2 + b) * 1024 + n * 64 + ks * 32 + g * 8;
    fqw[ks] = *(const bf16x8*)&qw[off];
    fqr[ks] = *(const bf16x8*)&qr[off];
  }
  float ef0v[4], dv[4];
  unsigned int smoff[4];
#pragma unroll
  for (int r = 0; r < 4; ++r) {
    int i = i0 + w * 16 + g * 4 + r;
    float e0 = ef0[bn * 1024 + i];
    ef0v[r] = e0;
    dv[r] = ef1[bn * 1024 + i] - e0;
    smoff[r] = ((unsigned)b << 20) | ((unsigned)i << 10) | (unsigned)lc;
  }
  float mrun[4], lsum[4];
  f32x4 accO[4] = {};
#pragma unroll
  for (int r = 0; r < 4; ++r) { mrun[r] = -3e38f; lsum[r] = 0.f; }

  const int srow = tid >> 3;
  const int sko = (tid & 7) * 8;

#pragma unroll
  for (int pp = 0; pp < 3; ++pp) {
    int jr = S0 + pp * 64 + srow;
    *(uint4*)&sKR[jr & 255][sko] =
        *(const uint4*)&krh[((size_t)jr * 2 + b) * 1024 + n * 64 + sko];
  }
  int j0 = js * 512;
  uint4 rK = *(const uint4*)&kh[((size_t)(j0 + srow) * 2 + b) * 1024 + n * 64 + sko];
  uint4 rV = *(const uint4*)&vT[((size_t)bn * 64 + srow) * 1024 + j0 + sko];
  uint4 rR = *(const uint4*)&krh[((size_t)(S0 + 192 + srow) * 2 + b) * 1024 + n * 64 + sko];

  for (int t = 0; t < 8; ++t) {
    j0 = (js * 8 + t) * 64;
    __syncthreads();
    *(uint4*)&sK[srow][sko] = rK;
    *(uint4*)&sVT[srow][sko] = rV;
    if (t < 7) {
      *(uint4*)&sKR[(S0 + 192 + t * 64 + srow) & 255][sko] = rR;
      int j0n = j0 + 64;
      rK = *(const uint4*)&kh[((size_t)(j0n + srow) * 2 + b) * 1024 + n * 64 + sko];
      rV = *(const uint4*)&vT[((size_t)bn * 64 + srow) * 1024 + j0n + sko];
      if (t < 6) {
        int jr = S0 + 256 + t * 64 + srow;
        if (jr > 2047) jr = 2047;
        rR = *(const uint4*)&krh[((size_t)jr * 2 + b) * 1024 + n * 64 + sko];
      }
    }
    unsigned int msv[4][4];
#pragma unroll
    for (int r = 0; r < 4; ++r)
#pragma unroll
      for (int nf = 0; nf < 4; ++nf)
        msv[r][nf] = segmask[smoff[r] + j0 + nf * 16];
    __syncthreads();

    const int base = S0 + t * 64 + (7 - w) * 16;
    f32x4 bdk[5];
#pragma unroll
    for (int k = 0; k < 5; ++k) {
      f32x4 a = {0.f, 0.f, 0.f, 0.f};
#pragma unroll
      for (int ks = 0; ks < 2; ++ks) {
        bf16x8 fk = *(const bf16x8*)&sKR[(base + k * 16 + lc) & 255][ks * 32 + g * 8];
        a = mfma16(fqr[ks], fk, a);
      }
      bdk[k] = a;
    }
    float p[4][4];
#pragma unroll
    for (int r = 0; r < 4; ++r) {
      const int a_ = g * 4 + r;
      const int srcl = (lane & 48) | ((lc + 15 - a_) & 15);
      float s0 = __shfl(bdk[0][r], srcl);
      float s1 = __shfl(bdk[1][r], srcl);
      float s2 = __shfl(bdk[2][r], srcl);
      float s3 = __shfl(bdk[3][r], srcl);
      float s4 = __shfl(bdk[4][r], srcl);
      const bool lo = lc <= a_;
#pragma unroll
      for (int nf = 0; nf < 4; ++nf) {
        unsigned int u = msv[r][nf];
        float sgv = bf2f((unsigned short)(u & 0xffffu));
        float mkv = bf2f((unsigned short)(u >> 16));
        float bdv = lo ? (nf == 0 ? s0 : nf == 1 ? s1 : nf == 2 ? s2 : s3)
                       : (nf == 0 ? s1 : nf == 1 ? s2 : nf == 2 ? s3 : s4);
        p[r][nf] = ef0v[r] + sgv * dv[r] + mkv + bdv;
      }
    }
    f32x4 aa[4];
#pragma unroll
    for (int nf = 0; nf < 4; ++nf) {
      f32x4 a = {0.f, 0.f, 0.f, 0.f};
#pragma unroll
      for (int ks = 0; ks < 2; ++ks) {
        bf16x8 fk = *(const bf16x8*)&sK[nf * 16 + lc][ks * 32 + g * 8];
        a = mfma16(fqw[ks], fk, a);
      }
      aa[nf] = a;
    }
#pragma unroll
    for (int r = 0; r < 4; ++r)
#pragma unroll
      for (int nf = 0; nf < 4; ++nf) p[r][nf] += aa[nf][r];

#pragma unroll
    for (int r = 0; r < 4; ++r) {
      float mt = fmaxf(fmaxf(p[r][0], p[r][1]), fmaxf(p[r][2], p[r][3]));
      mt = rmax16(mt);
      float mnew = fmaxf(mrun[r], mt);
      float corr = __expf(mrun[r] - mnew);
      mrun[r] = mnew;
      float se = 0.f;
#pragma unroll
      for (int nf = 0; nf < 4; ++nf) {
        float e = __expf(p[r][nf] - mnew);
        p[r][nf] = e;
        se += e;
      }
      se = rsum16(se);
      lsum[r] = lsum[r] * corr + se;
#pragma unroll
      for (int df = 0; df < 4; ++df) accO[df][r] *= corr;
#pragma unroll
      for (int nf = 0; nf < 4; ++nf)
        sP[w][g * 4 + r][nf * 16 + lc] = f2bf(p[r][nf]);
    }
#pragma unroll
    for (int ks = 0; ks < 2; ++ks) {
      bf16x8 fp = *(const bf16x8*)&sP[w][lc][ks * 32 + g * 8];
#pragma unroll
      for (int df = 0; df < 4; ++df) {
        bf16x8 fv = *(const bf16x8*)&sVT[df * 16 + lc][ks * 32 + g * 8];
        accO[df] = mfma16(fp, fv, accO[df]);
      }
    }
  }
#pragma unroll
  for (int r = 0; r < 4; ++r) {
    int i = i0 + w * 16 + g * 4 + r;
    size_t pb = ((size_t)(js * 32 + bn) * 1024 + i) * 64;
#pragma unroll
    for (int df = 0; df < 4; ++df) part[pb + df * 16 + lc] = accO[df][r];
    if (lc == 0) {
      size_t mb = (((size_t)js * 32 + bn) * 1024 + i) * 2;
      ml[mb] = mrun[r];
      ml[mb + 1] = lsum[r];
    }
  }
}

// ---------------- combine the two j-splits ----------------
__global__ __launch_bounds__(256) void combine_kernel(const float* __restrict__ part,
                                                      const float* __restrict__ ml,
                                                      unsigned short* __restrict__ av) {
  int gw = blockIdx.x * 4 + (threadIdx.x >> 6);
  int lane = threadIdx.x & 63;
  int bn = gw >> 10, i = gw & 1023;
  int b = bn >> 4, n = bn & 15;
  float m0 = ml[((size_t)bn * 1024 + i) * 2];
  float l0 = ml[((size_t)bn * 1024 + i) * 2 + 1];
  float m1 = ml[(((size_t)32 + bn) * 1024 + i) * 2];
  float l1 = ml[(((size_t)32 + bn) * 1024 + i) * 2 + 1];
  float mx = fmaxf(m0, m1);
  float w0 = __expf(m0 - mx), w1 = __expf(m1 - mx);
  float inv = 1.f / (l0 * w0 + l1 * w1);
  float o = part[((size_t)bn * 1024 + i) * 64 + lane] * w0 +
            part[(((size_t)32 + bn) * 1024 + i) * 64 + lane] * w1;
  av[((size_t)i * 2 + b) * 1024 + n * 64 + lane] = f2bf(o * inv);
}

// ---------------- residual + LayerNorm ----------------
__global__ __launch_bounds__(256) void ln_kernel(const float* __restrict__ gout,
                                                 const float* __restrict__ h,
                                                 const float* __restrict__ gamma,
                                                 const float* __restrict__ beta,
                                                 float* __restrict__ out) {
  __shared__ float red[8];
  const int row = blockIdx.x;
  const int tid = threadIdx.x;
  float x[4];
  float s = 0.f;
#pragma unroll
  for (int q = 0; q < 4; ++q) {
    int d = tid + q * 256;
    x[q] = gout[(size_t)row * 1024 + d] + h[(size_t)row * 1024 + d];
    s += x[q];
  }
#pragma unroll
  for (int m = 1; m < 64; m <<= 1) s += __shfl_xor(s, m);
  if ((tid & 63) == 0) red[tid >> 6] = s;
  __syncthreads();
  s = red[0] + red[1] + red[2] + red[3];
  float mu = s * (1.f / 1024.f);
  float v = 0.f;
#pragma unroll
  for (int q = 0; q < 4; ++q) {
    float dd = x[q] - mu;
    v += dd * dd;
  }
#pragma unroll
  for (int m = 1; m < 64; m <<= 1) v += __shfl_xor(v, m);
  if ((tid & 63) == 0) red[4 + (tid >> 6)] = v;
  __syncthreads();
  v = red[4] + red[5] + red[6] + red[7];
  float rstd = rsqrtf(v * (1.f / 1024.f) + 1e-12f);
#pragma unroll
  for (int q = 0; q < 4; ++q) {
    int d = tid + q * 256;
    out[(size_t)row * 1024 + d] = (x[q] - mu) * rstd * gamma[d] + beta[d];
  }
}

extern "C" void kernel_launch(void* const* d_in, const int* in_sizes, int n_in,
                              void* d_out, int out_size, void* d_ws, size_t ws_size,
                              hipStream_t stream) {
  const float* h = (const float*)d_in[0];
  const float* r = (const float*)d_in[1];
  const unsigned char* seg = (const unsigned char*)d_in[2];
  const float* mask = (const float*)d_in[3];
  const float* wq = (const float*)d_in[4];
  const float* wk = (const float*)d_in[5];
  const float* wv = (const float*)d_in[6];
  const float* wr = (const float*)d_in[7];
  const float* wo = (const float*)d_in[8];
  const float* rwb = (const float*)d_in[9];
  const float* rrb = (const float*)d_in[10];
  const float* rsb = (const float*)d_in[11];
  const float* seg_embed = (const float*)d_in[12];
  const float* gamma = (const float*)d_in[13];
  const float* beta = (const float*)d_in[14];
  float* out = (float*)d_out;

  char* ws = (char*)d_ws;
  size_t off = 0;
  auto alloc = [&](size_t bytes) {
    size_t cur = off;
    off = (off + bytes + 255) & ~(size_t)255;
    return cur;
  };
  unsigned short* hb = (unsigned short*)(ws + alloc(2048 * 1024 * 2));
  unsigned short* rb = (unsigned short*)(ws + alloc(4096 * 1024 * 2));
  unsigned short* wq_t = (unsigned short*)(ws + alloc(1024 * 1024 * 2));
  unsigned short* wk_t = (unsigned short*)(ws + alloc(1024 * 1024 * 2));
  unsigned short* wv_t = (unsigned short*)(ws + alloc(1024 * 1024 * 2));
  unsigned short* wr_t = (unsigned short*)(ws + alloc(1024 * 1024 * 2));
  unsigned short* wo_b = (unsigned short*)(ws + alloc(1024 * 1024 * 2));
  unsigned short* qwb = (unsigned short*)(ws + alloc(2048 * 1024 * 2));
  unsigned short* qrb = (unsigned short*)(ws + alloc(2048 * 1024 * 2));
  unsigned short* qsb = (unsigned short*)(ws + alloc(2048 * 1024 * 2));
  unsigned short* khb = (unsigned short*)(ws + alloc(2048 * 1024 * 2));
  unsigned short* vhb = (unsigned short*)(ws + alloc(2048 * 1024 * 2));
  unsigned short* krhb = (unsigned short*)(ws + alloc(4096 * 1024 * 2));
  unsigned short* vTb = (unsigned short*)(ws + alloc(2048 * 1024 * 2));
  float* ef0 = (float*)(ws + alloc(2048 * 16 * 4));
  float* ef1 = (float*)(ws + alloc(2048 * 16 * 4));
  unsigned int* segmask = (unsigned int*)(ws + alloc(2 * 1024 * 1024 * 4));
  unsigned short* avb = (unsigned short*)(ws + alloc(2048 * 1024 * 2));
  float* gout = (float*)(ws + alloc(2048 * 1024 * 4));
  float* part = (float*)(ws + alloc((size_t)2 * 32 * 1024 * 64 * 4));
  float* mlb = (float*)(ws + alloc((size_t)2 * 32 * 1024 * 2 * 4));
  (void)ws_size; (void)in_sizes; (void)n_in; (void)out_size;

  cast3_kernel<<<7168, 256, 0, stream>>>(h, r, wo, hb, rb, wo_b);
  transpose_cast4<<<dim3(32, 32, 4), 256, 0, stream>>>(wq, wk, wv, wr, wq_t, wk_t, wv_t, wr_t);
  segmask_kernel<<<4096, 256, 0, stream>>>(seg, mask, segmask);

  proj4_kernel<<<640, 512, 0, stream>>>(hb, rb, wq_t, wk_t, wv_t, wr_t, rwb, rrb, rsb,
                                        qwb, qrb, qsb, khb, vhb, krhb);

  transpose_v<<<dim3(16, 32), 256, 0, stream>>>(vhb, vTb);
  ef_kernel<<<8192, 256, 0, stream>>>(qsb, seg_embed, ef0, ef1);

  attn_kernel<<<dim3(32, 8, 2), 512, 0, stream>>>(qwb, qrb, khb, krhb, vTb,
                                                  ef0, ef1, segmask, part, mlb);
  combine_kernel<<<8192, 256, 0, stream>>>(part, mlb, avb);

  gemm64_out<<<dim3(8, 32), 512, 0, stream>>>(avb, wo_b, gout);
  ln_kernel<<<2048, 256, 0, stream>>>(gout, h, gamma, beta, out);
}

// Round 9
// 129.360 us; speedup vs baseline: 1.4093x; 1.0824x over previous
//
#include <hip/hip_runtime.h>

typedef __bf16 bf16x8 __attribute__((ext_vector_type(8)));
typedef float f32x4 __attribute__((ext_vector_type(4)));
typedef unsigned short us4 __attribute__((ext_vector_type(4)));

__device__ __forceinline__ unsigned short f2bf(float f) {
  unsigned int u = __builtin_bit_cast(unsigned int, f);
  u += 0x7fffu + ((u >> 16) & 1u);
  return (unsigned short)(u >> 16);
}
__device__ __forceinline__ float bf2f(unsigned short s) {
  unsigned int u = ((unsigned int)s) << 16;
  return __builtin_bit_cast(float, u);
}
__device__ __forceinline__ f32x4 mfma16(bf16x8 a, bf16x8 b, f32x4 c) {
  return __builtin_amdgcn_mfma_f32_16x16x32_bf16(a, b, c, 0, 0, 0);
}
__device__ __forceinline__ void gload16(const void* g, void* l) {
  __builtin_amdgcn_global_load_lds(
      (const __attribute__((address_space(1))) unsigned int*)g,
      (__attribute__((address_space(3))) unsigned int*)l, 16, 0, 0);
}
template <int CTRL>
__device__ __forceinline__ float dppf(float x) {
  return __builtin_bit_cast(
      float, __builtin_amdgcn_mov_dpp(__builtin_bit_cast(int, x), CTRL, 0xf, 0xf, true));
}
__device__ __forceinline__ float rmax16(float x) {
  x = fmaxf(x, dppf<0xB1>(x));
  x = fmaxf(x, dppf<0x4E>(x));
  x = fmaxf(x, dppf<0x124>(x));
  x = fmaxf(x, dppf<0x128>(x));
  return x;
}
__device__ __forceinline__ float rsum16(float x) {
  x += dppf<0xB1>(x);
  x += dppf<0x4E>(x);
  x += dppf<0x124>(x);
  x += dppf<0x128>(x);
  return x;
}

// ---------------- fused preprocessing: casts + weight transposes + segmask, one launch ----------------
__global__ __launch_bounds__(256) void pre_kernel(
    const float* __restrict__ h, const float* __restrict__ r, const float* __restrict__ wo,
    const float* __restrict__ w0, const float* __restrict__ w1,
    const float* __restrict__ w2, const float* __restrict__ w3,
    const unsigned char* __restrict__ seg, const float* __restrict__ mask,
    unsigned short* __restrict__ hb, unsigned short* __restrict__ rb,
    unsigned short* __restrict__ wo_b,
    unsigned short* __restrict__ o0, unsigned short* __restrict__ o1,
    unsigned short* __restrict__ o2, unsigned short* __restrict__ o3,
    unsigned int* __restrict__ segout) {
  __shared__ float t[32][33];
  const int bx = blockIdx.x;
  const int tid = threadIdx.x;
  if (bx < 7168) {
    // cast3: h (512K float4), r (1024K), wo (256K)
    int idx = bx * 256 + tid;
    const float* in;
    unsigned short* out;
    int o;
    if (idx < 524288) { in = h; out = hb; o = idx; }
    else if (idx < 1572864) { in = r; out = rb; o = idx - 524288; }
    else { in = wo; out = wo_b; o = idx - 1572864; }
    float4 v = ((const float4*)in)[o];
    us4 tt;
    tt[0] = f2bf(v.x); tt[1] = f2bf(v.y); tt[2] = f2bf(v.z); tt[3] = f2bf(v.w);
    *(us4*)&out[o * 4] = tt;
  } else if (bx < 11264) {
    // transpose+cast 4 weights
    int zz = bx - 7168;
    int z = zz >> 10, tt_ = zz & 1023;
    const float* in = z == 0 ? w0 : (z == 1 ? w1 : (z == 2 ? w2 : w3));
    unsigned short* out = z == 0 ? o0 : (z == 1 ? o1 : (z == 2 ? o2 : o3));
    int k0 = (tt_ >> 5) * 32;
    int n0 = (tt_ & 31) * 32;
    int rr = tid >> 5;
    int c = tid & 31;
#pragma unroll
    for (int s = 0; s < 4; ++s)
      t[rr + s * 8][c] = in[(k0 + rr + s * 8) * 1024 + n0 + c];
    __syncthreads();
#pragma unroll
    for (int s = 0; s < 4; ++s)
      out[(n0 + rr + s * 8) * 1024 + k0 + c] = f2bf(t[c][rr + s * 8]);
  } else {
    // segmask pack
    int ij = (bx - 11264) * 256 + tid;
    unsigned short sv = *(const unsigned short*)&seg[ij * 2];
    float2 mv = *(const float2*)&mask[(size_t)ij * 2];
    unsigned int q0 = ((unsigned int)f2bf(mv.x * -1e30f) << 16) | ((sv & 0xffu) ? 0x3f80u : 0u);
    unsigned int q1 = ((unsigned int)f2bf(mv.y * -1e30f) << 16) | ((sv >> 8) ? 0x3f80u : 0u);
    segout[ij] = q0;
    segout[1048576 + ij] = q1;
  }
}

// ---------------- all 4 projections: 128x128 tile, 8 waves, BK=64, 2-phase dbuf, swizzled
// (R7 proven structure) + fused ef epilogue ----------------
__global__ __launch_bounds__(512) void proj4_kernel(
    const unsigned short* __restrict__ hb, const unsigned short* __restrict__ rb,
    const unsigned short* __restrict__ wq_t, const unsigned short* __restrict__ wk_t,
    const unsigned short* __restrict__ wv_t, const unsigned short* __restrict__ wr_t,
    const float* __restrict__ rwb, const float* __restrict__ rrb, const float* __restrict__ rsb,
    const float* __restrict__ seg_embed,
    unsigned short* __restrict__ qwb, unsigned short* __restrict__ qrb,
    unsigned short* __restrict__ khb, unsigned short* __restrict__ vhb,
    unsigned short* __restrict__ krhb,
    float* __restrict__ ef0, float* __restrict__ ef1) {
  __shared__ unsigned short sA[2][128 * 64];
  __shared__ unsigned short sB[2][128 * 64];
  const int bx = blockIdx.x;
  int sel, rblk;
  const unsigned short* A;
  if (bx < 384) { sel = bx >> 7; rblk = bx & 127; A = hb; }
  else { sel = 3; rblk = bx - 384; A = rb; }
  const unsigned short* Bt = sel == 0 ? wq_t : (sel == 1 ? wk_t : (sel == 2 ? wv_t : wr_t));
  const int n0 = (rblk & 7) * 128, m0 = (rblk >> 3) * 128;
  const int tid = threadIdx.x, lane = tid & 63, w = tid >> 6;  // 8 waves
  const int wm = w >> 1, wn = w & 1, g = lane >> 4, lc = lane & 15;

  f32x4 acc[2][4] = {};

  auto STAGE = [&](int buf, int kt) {
#pragma unroll
    for (int s = 0; s < 2; ++s) {
      int c = s * 512 + tid;
      int row = c >> 3;
      int ko = ((c & 7) ^ (row & 7)) * 8;  // pre-swizzled global slot
      int lbase = (s * 512 + w * 64) * 8;  // linear LDS dest
      gload16(&A[(size_t)(m0 + row) * 1024 + kt + ko], &sA[buf][lbase]);
      gload16(&Bt[(size_t)(n0 + row) * 1024 + kt + ko], &sB[buf][lbase]);
    }
  };

  STAGE(0, 0);
  __syncthreads();

  for (int kt = 0; kt < 1024; kt += 64) {
    const int cur = (kt >> 6) & 1;
    if (kt < 960) STAGE(cur ^ 1, kt + 64);
    bf16x8 af[2][2], bfr[4][2];
#pragma unroll
    for (int ks = 0; ks < 2; ++ks) {
#pragma unroll
      for (int mi = 0; mi < 2; ++mi) {
        int ra = wm * 32 + mi * 16 + lc;
        af[mi][ks] = *(const bf16x8*)&sA[cur][ra * 64 + (((ks * 4 + g) ^ (ra & 7)) * 8)];
      }
#pragma unroll
      for (int ni = 0; ni < 4; ++ni) {
        int rb_ = wn * 64 + ni * 16 + lc;
        bfr[ni][ks] = *(const bf16x8*)&sB[cur][rb_ * 64 + (((ks * 4 + g) ^ (rb_ & 7)) * 8)];
      }
    }
#pragma unroll
    for (int ks = 0; ks < 2; ++ks)
#pragma unroll
      for (int mi = 0; mi < 2; ++mi)
#pragma unroll
        for (int ni = 0; ni < 4; ++ni)
          acc[mi][ni] = mfma16(af[mi][ks], bfr[ni][ks], acc[mi][ni]);
    __syncthreads();
  }

  if (sel == 0) {
    // q projection: write qw,qr (pre-scaled) and compute ef0/ef1 in-register
    const int hn = (n0 >> 6) + wn;  // head index 0..15
    float se0v[4], se1v[4], bwv[4], brv[4], bsv[4];
#pragma unroll
    for (int ni = 0; ni < 4; ++ni) {
      int col = n0 + wn * 64 + ni * 16 + lc;
      se0v[ni] = seg_embed[hn * 64 + ni * 16 + lc];
      se1v[ni] = seg_embed[1024 + hn * 64 + ni * 16 + lc];
      bwv[ni] = rwb[col];
      brv[ni] = rrb[col];
      bsv[ni] = rsb[col];
    }
#pragma unroll
    for (int mi = 0; mi < 2; ++mi) {
      int rowb = m0 + wm * 32 + mi * 16 + g * 4;
#pragma unroll
      for (int r = 0; r < 4; ++r) {
        float e0 = 0.f, e1 = 0.f;
#pragma unroll
        for (int ni = 0; ni < 4; ++ni) {
          int col = n0 + wn * 64 + ni * 16 + lc;
          float v = acc[mi][ni][r];
          size_t idx = (size_t)(rowb + r) * 1024 + col;
          qwb[idx] = f2bf((v + bwv[ni]) * 0.125f);
          qrb[idx] = f2bf((v + brv[ni]) * 0.125f);
          float qsv = (v + bsv[ni]) * 0.125f;
          e0 += qsv * se0v[ni];
          e1 += qsv * se1v[ni];
        }
        e0 = rsum16(e0);
        e1 = rsum16(e1);
        if (lc == 0) {
          int ib = rowb + r;
          int i = ib >> 1, b = ib & 1;
          ef0[(b * 16 + hn) * 1024 + i] = e0;
          ef1[(b * 16 + hn) * 1024 + i] = e1;
        }
      }
    }
  } else {
#pragma unroll
    for (int ni = 0; ni < 4; ++ni) {
      int col = n0 + wn * 64 + ni * 16 + lc;
#pragma unroll
      for (int mi = 0; mi < 2; ++mi) {
        int rowb = m0 + wm * 32 + mi * 16 + g * 4;
#pragma unroll
        for (int r = 0; r < 4; ++r) {
          float v = acc[mi][ni][r];
          size_t idx = (size_t)(rowb + r) * 1024 + col;
          if (sel == 1) khb[idx] = f2bf(v);
          else if (sel == 2) vhb[idx] = f2bf(v);
          else krhb[idx] = f2bf(v);
        }
      }
    }
  }
}

// ---------------- out-projection: 64x128 tile, 8 waves, BK=64, 2-phase dbuf, swizzled ----------------
__global__ __launch_bounds__(512) void gemm64_out(const unsigned short* __restrict__ A,
                                                  const unsigned short* __restrict__ Bt,
                                                  float* __restrict__ C) {
  __shared__ unsigned short sA[2][64 * 64];
  __shared__ unsigned short sB[2][128 * 64];
  const int tid = threadIdx.x, lane = tid & 63, w = tid >> 6;  // 8 waves
  const int wm = w >> 2, wn = w & 3, g = lane >> 4, lc = lane & 15;
  const int m0 = blockIdx.y * 64, n0 = blockIdx.x * 128;
  f32x4 acc[2][2] = {};

  auto STAGE = [&](int buf, int kt) {
    {
      int c = tid;
      int row = c >> 3;
      int ko = ((c & 7) ^ (row & 7)) * 8;
      gload16(&A[(size_t)(m0 + row) * 1024 + kt + ko], &sA[buf][w * 64 * 8]);
    }
#pragma unroll
    for (int s = 0; s < 2; ++s) {
      int c = s * 512 + tid;
      int row = c >> 3;
      int ko = ((c & 7) ^ (row & 7)) * 8;
      gload16(&Bt[(size_t)(n0 + row) * 1024 + kt + ko], &sB[buf][(s * 512 + w * 64) * 8]);
    }
  };

  STAGE(0, 0);
  __syncthreads();

  for (int kt = 0; kt < 1024; kt += 64) {
    const int cur = (kt >> 6) & 1;
    if (kt < 960) STAGE(cur ^ 1, kt + 64);
    bf16x8 af[2][2], bfr[2][2];
#pragma unroll
    for (int ks = 0; ks < 2; ++ks) {
#pragma unroll
      for (int mi = 0; mi < 2; ++mi) {
        int ra = wm * 32 + mi * 16 + lc;
        af[mi][ks] = *(const bf16x8*)&sA[cur][ra * 64 + (((ks * 4 + g) ^ (ra & 7)) * 8)];
      }
#pragma unroll
      for (int ni = 0; ni < 2; ++ni) {
        int rb_ = wn * 32 + ni * 16 + lc;
        bfr[ni][ks] = *(const bf16x8*)&sB[cur][rb_ * 64 + (((ks * 4 + g) ^ (rb_ & 7)) * 8)];
      }
    }
#pragma unroll
    for (int ks = 0; ks < 2; ++ks)
#pragma unroll
      for (int mi = 0; mi < 2; ++mi)
#pragma unroll
        for (int ni = 0; ni < 2; ++ni)
          acc[mi][ni] = mfma16(af[mi][ks], bfr[ni][ks], acc[mi][ni]);
    __syncthreads();
  }
#pragma unroll
  for (int ni = 0; ni < 2; ++ni) {
    int col = n0 + wn * 32 + ni * 16 + lc;
#pragma unroll
    for (int mi = 0; mi < 2; ++mi) {
      int rowb = m0 + wm * 32 + mi * 16 + g * 4;
#pragma unroll
      for (int r = 0; r < 4; ++r)
        C[(size_t)(rowb + r) * 1024 + col] = acc[mi][ni][r];
    }
  }
}

// ---------------- V transpose ----------------
__global__ __launch_bounds__(256) void transpose_v(const unsigned short* __restrict__ vh,
                                                   unsigned short* __restrict__ vT) {
  __shared__ unsigned short t[64][65];
  const int bn = blockIdx.y, j0 = blockIdx.x * 64;
  const int b = bn >> 4, n = bn & 15;
  const int r = threadIdx.x >> 4;
  const int c4 = (threadIdx.x & 15) * 4;
#pragma unroll
  for (int s = 0; s < 4; ++s) {
    int j = r + s * 16;
    us4 v = *(const us4*)&vh[((size_t)(j0 + j) * 2 + b) * 1024 + n * 64 + c4];
    t[j][c4 + 0] = v[0]; t[j][c4 + 1] = v[1]; t[j][c4 + 2] = v[2]; t[j][c4 + 3] = v[3];
  }
  __syncthreads();
#pragma unroll
  for (int s = 0; s < 4; ++s) {
    int d = r + s * 16;
    us4 v;
    v[0] = t[c4 + 0][d]; v[1] = t[c4 + 1][d]; v[2] = t[c4 + 2][d]; v[3] = t[c4 + 3][d];
    *(us4*)&vT[((size_t)bn * 64 + d) * 1024 + j0 + c4] = v;
  }
}

// ---------------- fused relative attention: BI=128, 8 waves, j-split x2 ----------------
__global__ __launch_bounds__(512, 4) void attn_kernel(
    const unsigned short* __restrict__ qw, const unsigned short* __restrict__ qr,
    const unsigned short* __restrict__ kh, const unsigned short* __restrict__ krh,
    const unsigned short* __restrict__ vT,
    const float* __restrict__ ef0, const float* __restrict__ ef1,
    const unsigned int* __restrict__ segmask,
    float* __restrict__ part, float* __restrict__ ml) {
  __shared__ unsigned short sK[64][72];
  __shared__ unsigned short sVT[64][72];
  __shared__ unsigned short sKR[256][72];  // circular band, slot = jr & 255
  __shared__ unsigned short sP[8][16][80];

  const int tid = threadIdx.x, lane = tid & 63, w = tid >> 6;  // w: 0..7
  const int g = lane >> 4, lc = lane & 15;
  const int bn = blockIdx.x, b = bn >> 4, n = bn & 15;
  const int i0 = blockIdx.y * 128;
  const int js = blockIdx.z;
  const int S0 = 1024 + js * 512 - i0 - 127;

  bf16x8 fqw[2], fqr[2];
  const int qrow = i0 + w * 16 + lc;
#pragma unroll
  for (int ks = 0; ks < 2; ++ks) {
    size_t off = ((size_t)qrow * 2 + b) * 1024 + n * 64 + ks * 32 + g * 8;
    fqw[ks] = *(const bf16x8*)&qw[off];
    fqr[ks] = *(const bf16x8*)&qr[off];
  }
  float ef0v[4], dv[4];
  unsigned int smoff[4];
#pragma unroll
  for (int r = 0; r < 4; ++r) {
    int i = i0 + w * 16 + g * 4 + r;
    float e0 = ef0[bn * 1024 + i];
    ef0v[r] = e0;
    dv[r] = ef1[bn * 1024 + i] - e0;
    smoff[r] = ((unsigned)b << 20) | ((unsigned)i << 10) | (unsigned)lc;
  }
  float mrun[4], lsum[4];
  f32x4 accO[4] = {};
#pragma unroll
  for (int r = 0; r < 4; ++r) { mrun[r] = -3e38f; lsum[r] = 0.f; }

  const int srow = tid >> 3;
  const int sko = (tid & 7) * 8;

#pragma unroll
  for (int pp = 0; pp < 3; ++pp) {
    int jr = S0 + pp * 64 + srow;
    *(uint4*)&sKR[jr & 255][sko] =
        *(const uint4*)&krh[((size_t)jr * 2 + b) * 1024 + n * 64 + sko];
  }
  int j0 = js * 512;
  uint4 rK = *(const uint4*)&kh[((size_t)(j0 + srow) * 2 + b) * 1024 + n * 64 + sko];
  uint4 rV = *(const uint4*)&vT[((size_t)bn * 64 + srow) * 1024 + j0 + sko];
  uint4 rR = *(const uint4*)&krh[((size_t)(S0 + 192 + srow) * 2 + b) * 1024 + n * 64 + sko];

  for (int t = 0; t < 8; ++t) {
    j0 = (js * 8 + t) * 64;
    __syncthreads();
    *(uint4*)&sK[srow][sko] = rK;
    *(uint4*)&sVT[srow][sko] = rV;
    if (t < 7) {
      *(uint4*)&sKR[(S0 + 192 + t * 64 + srow) & 255][sko] = rR;
      int j0n = j0 + 64;
      rK = *(const uint4*)&kh[((size_t)(j0n + srow) * 2 + b) * 1024 + n * 64 + sko];
      rV = *(const uint4*)&vT[((size_t)bn * 64 + srow) * 1024 + j0n + sko];
      if (t < 6) {
        int jr = S0 + 256 + t * 64 + srow;
        if (jr > 2047) jr = 2047;
        rR = *(const uint4*)&krh[((size_t)jr * 2 + b) * 1024 + n * 64 + sko];
      }
    }
    unsigned int msv[4][4];
#pragma unroll
    for (int r = 0; r < 4; ++r)
#pragma unroll
      for (int nf = 0; nf < 4; ++nf)
        msv[r][nf] = segmask[smoff[r] + j0 + nf * 16];
    __syncthreads();

    const int base = S0 + t * 64 + (7 - w) * 16;
    f32x4 bdk[5];
#pragma unroll
    for (int k = 0; k < 5; ++k) {
      f32x4 a = {0.f, 0.f, 0.f, 0.f};
#pragma unroll
      for (int ks = 0; ks < 2; ++ks) {
        bf16x8 fk = *(const bf16x8*)&sKR[(base + k * 16 + lc) & 255][ks * 32 + g * 8];
        a = mfma16(fqr[ks], fk, a);
      }
      bdk[k] = a;
    }
    float p[4][4];
#pragma unroll
    for (int r = 0; r < 4; ++r) {
      const int a_ = g * 4 + r;
      const int srcl = (lane & 48) | ((lc + 15 - a_) & 15);
      float s0 = __shfl(bdk[0][r], srcl);
      float s1 = __shfl(bdk[1][r], srcl);
      float s2 = __shfl(bdk[2][r], srcl);
      float s3 = __shfl(bdk[3][r], srcl);
      float s4 = __shfl(bdk[4][r], srcl);
      const bool lo = lc <= a_;
#pragma unroll
      for (int nf = 0; nf < 4; ++nf) {
        unsigned int u = msv[r][nf];
        float sgv = bf2f((unsigned short)(u & 0xffffu));
        float mkv = bf2f((unsigned short)(u >> 16));
        float bdv = lo ? (nf == 0 ? s0 : nf == 1 ? s1 : nf == 2 ? s2 : s3)
                       : (nf == 0 ? s1 : nf == 1 ? s2 : nf == 2 ? s3 : s4);
        p[r][nf] = ef0v[r] + sgv * dv[r] + mkv + bdv;
      }
    }
    f32x4 aa[4];
#pragma unroll
    for (int nf = 0; nf < 4; ++nf) {
      f32x4 a = {0.f, 0.f, 0.f, 0.f};
#pragma unroll
      for (int ks = 0; ks < 2; ++ks) {
        bf16x8 fk = *(const bf16x8*)&sK[nf * 16 + lc][ks * 32 + g * 8];
        a = mfma16(fqw[ks], fk, a);
      }
      aa[nf] = a;
    }
#pragma unroll
    for (int r = 0; r < 4; ++r)
#pragma unroll
      for (int nf = 0; nf < 4; ++nf) p[r][nf] += aa[nf][r];

#pragma unroll
    for (int r = 0; r < 4; ++r) {
      float mt = fmaxf(fmaxf(p[r][0], p[r][1]), fmaxf(p[r][2], p[r][3]));
      mt = rmax16(mt);
      float mnew = fmaxf(mrun[r], mt);
      float corr = __expf(mrun[r] - mnew);
      mrun[r] = mnew;
      float se = 0.f;
#pragma unroll
      for (int nf = 0; nf < 4; ++nf) {
        float e = __expf(p[r][nf] - mnew);
        p[r][nf] = e;
        se += e;
      }
      se = rsum16(se);
      lsum[r] = lsum[r] * corr + se;
#pragma unroll
      for (int df = 0; df < 4; ++df) accO[df][r] *= corr;
#pragma unroll
      for (int nf = 0; nf < 4; ++nf)
        sP[w][g * 4 + r][nf * 16 + lc] = f2bf(p[r][nf]);
    }
#pragma unroll
    for (int ks = 0; ks < 2; ++ks) {
      bf16x8 fp = *(const bf16x8*)&sP[w][lc][ks * 32 + g * 8];
#pragma unroll
      for (int df = 0; df < 4; ++df) {
        bf16x8 fv = *(const bf16x8*)&sVT[df * 16 + lc][ks * 32 + g * 8];
        accO[df] = mfma16(fp, fv, accO[df]);
      }
    }
  }
#pragma unroll
  for (int r = 0; r < 4; ++r) {
    int i = i0 + w * 16 + g * 4 + r;
    size_t pb = ((size_t)(js * 32 + bn) * 1024 + i) * 64;
#pragma unroll
    for (int df = 0; df < 4; ++df) part[pb + df * 16 + lc] = accO[df][r];
    if (lc == 0) {
      size_t mb = (((size_t)js * 32 + bn) * 1024 + i) * 2;
      ml[mb] = mrun[r];
      ml[mb + 1] = lsum[r];
    }
  }
}

// ---------------- combine the two j-splits ----------------
__global__ __launch_bounds__(256) void combine_kernel(const float* __restrict__ part,
                                                      const float* __restrict__ ml,
                                                      unsigned short* __restrict__ av) {
  int gw = blockIdx.x * 4 + (threadIdx.x >> 6);
  int lane = threadIdx.x & 63;
  int bn = gw >> 10, i = gw & 1023;
  int b = bn >> 4, n = bn & 15;
  float m0 = ml[((size_t)bn * 1024 + i) * 2];
  float l0 = ml[((size_t)bn * 1024 + i) * 2 + 1];
  float m1 = ml[(((size_t)32 + bn) * 1024 + i) * 2];
  float l1 = ml[(((size_t)32 + bn) * 1024 + i) * 2 + 1];
  float mx = fmaxf(m0, m1);
  float w0 = __expf(m0 - mx), w1 = __expf(m1 - mx);
  float inv = 1.f / (l0 * w0 + l1 * w1);
  float o = part[((size_t)bn * 1024 + i) * 64 + lane] * w0 +
            part[(((size_t)32 + bn) * 1024 + i) * 64 + lane] * w1;
  av[((size_t)i * 2 + b) * 1024 + n * 64 + lane] = f2bf(o * inv);
}

// ---------------- residual + LayerNorm ----------------
__global__ __launch_bounds__(256) void ln_kernel(const float* __restrict__ gout,
                                                 const float* __restrict__ h,
                                                 const float* __restrict__ gamma,
                                                 const float* __restrict__ beta,
                                                 float* __restrict__ out) {
  __shared__ float red[8];
  const int row = blockIdx.x;
  const int tid = threadIdx.x;
  float x[4];
  float s = 0.f;
#pragma unroll
  for (int q = 0; q < 4; ++q) {
    int d = tid + q * 256;
    x[q] = gout[(size_t)row * 1024 + d] + h[(size_t)row * 1024 + d];
    s += x[q];
  }
#pragma unroll
  for (int m = 1; m < 64; m <<= 1) s += __shfl_xor(s, m);
  if ((tid & 63) == 0) red[tid >> 6] = s;
  __syncthreads();
  s = red[0] + red[1] + red[2] + red[3];
  float mu = s * (1.f / 1024.f);
  float v = 0.f;
#pragma unroll
  for (int q = 0; q < 4; ++q) {
    float dd = x[q] - mu;
    v += dd * dd;
  }
#pragma unroll
  for (int m = 1; m < 64; m <<= 1) v += __shfl_xor(v, m);
  if ((tid & 63) == 0) red[4 + (tid >> 6)] = v;
  __syncthreads();
  v = red[4] + red[5] + red[6] + red[7];
  float rstd = rsqrtf(v * (1.f / 1024.f) + 1e-12f);
#pragma unroll
  for (int q = 0; q < 4; ++q) {
    int d = tid + q * 256;
    out[(size_t)row * 1024 + d] = (x[q] - mu) * rstd * gamma[d] + beta[d];
  }
}

extern "C" void kernel_launch(void* const* d_in, const int* in_sizes, int n_in,
                              void* d_out, int out_size, void* d_ws, size_t ws_size,
                              hipStream_t stream) {
  const float* h = (const float*)d_in[0];
  const float* r = (const float*)d_in[1];
  const unsigned char* seg = (const unsigned char*)d_in[2];
  const float* mask = (const float*)d_in[3];
  const float* wq = (const float*)d_in[4];
  const float* wk = (const float*)d_in[5];
  const float* wv = (const float*)d_in[6];
  const float* wr = (const float*)d_in[7];
  const float* wo = (const float*)d_in[8];
  const float* rwb = (const float*)d_in[9];
  const float* rrb = (const float*)d_in[10];
  const float* rsb = (const float*)d_in[11];
  const float* seg_embed = (const float*)d_in[12];
  const float* gamma = (const float*)d_in[13];
  const float* beta = (const float*)d_in[14];
  float* out = (float*)d_out;

  char* ws = (char*)d_ws;
  size_t off = 0;
  auto alloc = [&](size_t bytes) {
    size_t cur = off;
    off = (off + bytes + 255) & ~(size_t)255;
    return cur;
  };
  unsigned short* hb = (unsigned short*)(ws + alloc(2048 * 1024 * 2));
  unsigned short* rb = (unsigned short*)(ws + alloc(4096 * 1024 * 2));
  unsigned short* wq_t = (unsigned short*)(ws + alloc(1024 * 1024 * 2));
  unsigned short* wk_t = (unsigned short*)(ws + alloc(1024 * 1024 * 2));
  unsigned short* wv_t = (unsigned short*)(ws + alloc(1024 * 1024 * 2));
  unsigned short* wr_t = (unsigned short*)(ws + alloc(1024 * 1024 * 2));
  unsigned short* wo_b = (unsigned short*)(ws + alloc(1024 * 1024 * 2));
  unsigned short* qwb = (unsigned short*)(ws + alloc(2048 * 1024 * 2));
  unsigned short* qrb = (unsigned short*)(ws + alloc(2048 * 1024 * 2));
  unsigned short* khb = (unsigned short*)(ws + alloc(2048 * 1024 * 2));
  unsigned short* vhb = (unsigned short*)(ws + alloc(2048 * 1024 * 2));
  unsigned short* krhb = (unsigned short*)(ws + alloc(4096 * 1024 * 2));
  unsigned short* vTb = (unsigned short*)(ws + alloc(2048 * 1024 * 2));
  float* ef0 = (float*)(ws + alloc(2048 * 16 * 4));
  float* ef1 = (float*)(ws + alloc(2048 * 16 * 4));
  unsigned int* segmask = (unsigned int*)(ws + alloc(2 * 1024 * 1024 * 4));
  unsigned short* avb = (unsigned short*)(ws + alloc(2048 * 1024 * 2));
  float* gout = (float*)(ws + alloc(2048 * 1024 * 4));
  float* part = (float*)(ws + alloc((size_t)2 * 32 * 1024 * 64 * 4));
  float* mlb = (float*)(ws + alloc((size_t)2 * 32 * 1024 * 2 * 4));
  (void)ws_size; (void)in_sizes; (void)n_in; (void)out_size;

  pre_kernel<<<15360, 256, 0, stream>>>(h, r, wo, wq, wk, wv, wr, seg, mask,
                                        hb, rb, wo_b, wq_t, wk_t, wv_t, wr_t, segmask);

  proj4_kernel<<<640, 512, 0, stream>>>(hb, rb, wq_t, wk_t, wv_t, wr_t, rwb, rrb, rsb,
                                        seg_embed, qwb, qrb, khb, vhb, krhb, ef0, ef1);

  transpose_v<<<dim3(16, 32), 256, 0, stream>>>(vhb, vTb);

  attn_kernel<<<dim3(32, 8, 2), 512, 0, stream>>>(qwb, qrb, khb, krhb, vTb,
                                                  ef0, ef1, segmask, part, mlb);
  combine_kernel<<<8192, 256, 0, stream>>>(part, mlb, avb);

  gemm64_out<<<dim3(8, 32), 512, 0, stream>>>(avb, wo_b, gout);
  ln_kernel<<<2048, 256, 0, stream>>>(gout, h, gamma, beta, out);
}